// Round 12
// baseline (1366.016 us; speedup 1.0000x reference)
//
#include <hip/hip_runtime.h>
#include <hip/hip_bf16.h>

// ---------------------------------------------------------------------------
// Transformer layer: LN1 -> QKV GEMM -> QKnorm+RoPE -> flash attn -> outproj
//                    (+res) -> LN2 -> SwiGLU FFN (+res)
// B=2 S=2048 DIM=1024 H=16 HD=64 FFN=4096. fp32 I/O, bf16 MFMA compute.
// R12: gemm256 BK=32, LDS 64KB -> 2 blocks/CU co-resident (m114 inter-block
//      overlap hides the per-tile barrier convoy that 1-block/CU exposed).
//      launch_bounds(512,4). De-phased loop (R11) otherwise unchanged.
// ---------------------------------------------------------------------------

typedef __bf16 bf16_t;
typedef bf16_t bf16x8 __attribute__((ext_vector_type(8)));
typedef bf16_t bf16x4 __attribute__((ext_vector_type(4)));
typedef float  f32x4  __attribute__((ext_vector_type(4)));
typedef float  f32x16 __attribute__((ext_vector_type(16)));

#define DIM   1024
#define HEADS 16
#define HD    64
#define FFND  4096
#define NB    2
#define SEQ   2048
#define NTOK  (NB * SEQ)   // 4096

#define GLOAD16(gp, lp) __builtin_amdgcn_global_load_lds( \
    (const __attribute__((address_space(1))) void*)(gp),  \
    (__attribute__((address_space(3))) void*)(lp), 16, 0, 0)

#define CVTPK(lo, hi_) ({ unsigned r_;                                        \
  asm("v_cvt_pk_bf16_f32 %0, %1, %2" : "=v"(r_) : "v"(lo), "v"(hi_)); r_; })
#define PLSWAP(a, b) asm("v_permlane32_swap_b32 %0, %1" : "+v"(a), "+v"(b))
#define SBAR() asm volatile("s_barrier" ::: "memory")

// ---------------- fp32 -> bf16 convert, all 5 weights in one launch --------
#define F2B_S0 786432
#define F2B_S1 262144
#define F2B_S2 1048576
#define F2B_S3 1048576
#define F2B_S4 1048576
#define F2B_C1 (F2B_S0)
#define F2B_C2 (F2B_C1 + F2B_S1)
#define F2B_C3 (F2B_C2 + F2B_S2)
#define F2B_C4 (F2B_C3 + F2B_S3)
#define F2B_N  (F2B_C4 + F2B_S4)

__global__ void f2bf_all_kernel(const float* __restrict__ s0, const float* __restrict__ s1,
                                const float* __restrict__ s2, const float* __restrict__ s3,
                                const float* __restrict__ s4,
                                bf16_t* __restrict__ d0, bf16_t* __restrict__ d1,
                                bf16_t* __restrict__ d2, bf16_t* __restrict__ d3,
                                bf16_t* __restrict__ d4) {
  int idx = blockIdx.x * blockDim.x + threadIdx.x;
  int stride = gridDim.x * blockDim.x;
  for (; idx < F2B_N; idx += stride) {
    const float* src; bf16_t* dst; int i;
    if (idx < F2B_C1)      { src = s0; dst = d0; i = idx; }
    else if (idx < F2B_C2) { src = s1; dst = d1; i = idx - F2B_C1; }
    else if (idx < F2B_C3) { src = s2; dst = d2; i = idx - F2B_C2; }
    else if (idx < F2B_C4) { src = s3; dst = d3; i = idx - F2B_C3; }
    else                   { src = s4; dst = d4; i = idx - F2B_C4; }
    float4 v = reinterpret_cast<const float4*>(src)[i];
    bf16x4 o;
    o[0] = (bf16_t)v.x; o[1] = (bf16_t)v.y; o[2] = (bf16_t)v.z; o[3] = (bf16_t)v.w;
    reinterpret_cast<bf16x4*>(dst)[i] = o;
  }
}

// ---------------- LayerNorm (one token per block, 256 thr) ----------------
__global__ __launch_bounds__(256) void ln_kernel(
    const float* __restrict__ x, const float* __restrict__ g,
    const float* __restrict__ b, bf16_t* __restrict__ out) {
  int t = blockIdx.x;
  int i = threadIdx.x;
  float4 v = reinterpret_cast<const float4*>(x + (size_t)t * DIM)[i];
  float s  = v.x + v.y + v.z + v.w;
  float s2 = v.x * v.x + v.y * v.y + v.z * v.z + v.w * v.w;
#pragma unroll
  for (int off = 32; off > 0; off >>= 1) {
    s  += __shfl_down(s, off, 64);
    s2 += __shfl_down(s2, off, 64);
  }
  __shared__ float red[2][4];
  int wid = i >> 6, lane = i & 63;
  if (lane == 0) { red[0][wid] = s; red[1][wid] = s2; }
  __syncthreads();
  float S  = red[0][0] + red[0][1] + red[0][2] + red[0][3];
  float S2 = red[1][0] + red[1][1] + red[1][2] + red[1][3];
  float mean = S * (1.0f / DIM);
  float var  = S2 * (1.0f / DIM) - mean * mean;
  float r = rsqrtf(var + 1e-6f);
  float vv[4] = {v.x, v.y, v.z, v.w};
  bf16x4 o;
#pragma unroll
  for (int j = 0; j < 4; ++j) {
    int d = i * 4 + j;
    o[j] = (bf16_t)((vv[j] - mean) * r * g[d] + b[d]);
  }
  *reinterpret_cast<bf16x4*>(out + (size_t)t * DIM + i * 4) = o;
}

// ---------------- gemm256: 256x256 tile, BK=32, 8 waves, 2 blocks/CU -------
// OUT_MODE: 1 = bf16 + bias; 2 = fp32 partial (slice blockIdx.z, no bias);
//           3 = bf16 silu(comp)*(acc+bias)  [SwiGLU fused w3 epilogue]
// LDS 64KB (2dbuf x [256][32] x A,B) -> 2 blocks/CU: inter-block wave overlap
// hides the per-tile vmcnt+barrier convoy. Per tile/wave: 4 gload_lds stage,
// 12 ds_read_b128, 32 MFMA, compiler-interleaved (no intra-tile fences).
template <int OUT_MODE>
__global__ __launch_bounds__(512, 4) void gemm256(
    const bf16_t* __restrict__ A, const bf16_t* __restrict__ B,
    const float* __restrict__ bias, const bf16_t* __restrict__ comp,
    void* __restrict__ Cout, int M, int N, int Kfull, int Klen) {
  __shared__ __align__(16) bf16_t Al[2][256][32];
  __shared__ __align__(16) bf16_t Bl[2][256][32];
  const int nTn = N >> 8;
  const int nwg = gridDim.x;
  const int bid = blockIdx.x;
  const int swz = ((nwg & 7) == 0) ? ((bid & 7) * (nwg >> 3) + (bid >> 3)) : bid;
  const int bm = swz / nTn, bn = swz % nTn;
  const int k0base = blockIdx.z * Klen;
  const int NT = Klen >> 5;                      // BK = 32
  const int tid = threadIdx.x, wid = tid >> 6, lane = tid & 63;
  const int wm2 = wid >> 2, wn = wid & 3;        // 2 x 4 waves
  const int lr = lane & 15, lg = lane >> 4;
  // staging (per wave, 16-row segment, gemm_bt-verified granule swizzle)
  const int sr4 = lane >> 2;                     // 0..15 row within segment
  const int sg  = lane & 3;
  const int cS  = ((sg ^ ((sr4 >> 1) & 3)) << 3);  // swizzled src col (elems)
  const int swg = ((lg ^ ((lr >> 1) & 3)) << 3);   // swizzled read granule
  const bf16_t* Abase = A + (size_t)(bm * 256 + wid * 16 + sr4) * Kfull + k0base + cS;
  const bf16_t* Bbase = B + (size_t)(bn * 256 + wid * 16 + sr4) * Kfull + k0base + cS;

#define STAGE_A(buf, h, t)                                                    \
  GLOAD16(Abase + (size_t)(h) * 128 * Kfull + (t) * 32,                       \
          &Al[buf][(h) * 128 + wid * 16][0])
#define STAGE_B(buf, h, t)                                                    \
  GLOAD16(Bbase + (size_t)(h) * 128 * Kfull + (t) * 32,                       \
          &Bl[buf][(h) * 128 + wid * 16][0])

  f32x4 acc[8][4] = {};
  STAGE_A(0, 0, 0); STAGE_A(0, 1, 0); STAGE_B(0, 0, 0); STAGE_B(0, 1, 0);

  for (int t = 0; t < NT; ++t) {
    const int cur = t & 1, nxt = cur ^ 1;
    asm volatile("s_waitcnt vmcnt(0)" ::: "memory");   // tile t landed (mine)
    SBAR();                                            // all waves: t visible,
                                                       // t-1 reads consumed
    if (t + 1 < NT) {                                  // stage t+1
      STAGE_A(nxt, 0, t + 1); STAGE_A(nxt, 1, t + 1);
      STAGE_B(nxt, 0, t + 1); STAGE_B(nxt, 1, t + 1);
    }
    bf16x8 af[8], bfr[4];
#pragma unroll
    for (int nf = 0; nf < 4; ++nf) {
      const int row = wn * 64 + nf * 16 + lr;
      bfr[nf] = *reinterpret_cast<const bf16x8*>(&Bl[cur][row][swg]);
    }
#pragma unroll
    for (int mf = 0; mf < 8; ++mf) {
      const int row = wm2 * 128 + mf * 16 + lr;
      af[mf] = *reinterpret_cast<const bf16x8*>(&Al[cur][row][swg]);
    }
    __builtin_amdgcn_s_setprio(1);
#pragma unroll
    for (int mf = 0; mf < 8; ++mf)
#pragma unroll
      for (int nf = 0; nf < 4; ++nf)
        acc[mf][nf] = __builtin_amdgcn_mfma_f32_16x16x32_bf16(af[mf], bfr[nf], acc[mf][nf], 0, 0, 0);
    __builtin_amdgcn_s_setprio(0);
  }
#undef STAGE_A
#undef STAGE_B
  const int r0 = lg * 4;
#pragma unroll
  for (int mf = 0; mf < 8; ++mf) {
#pragma unroll
    for (int r = 0; r < 4; ++r) {
      const int row = bm * 256 + wm2 * 128 + mf * 16 + r0 + r;
#pragma unroll
      for (int nf = 0; nf < 4; ++nf) {
        const int col = bn * 256 + wn * 64 + nf * 16 + lr;
        float v = acc[mf][nf][r];
        if (OUT_MODE == 1) {
          v += bias[col];
          reinterpret_cast<bf16_t*>(Cout)[(size_t)row * N + col] = (bf16_t)v;
        } else if (OUT_MODE == 2) {
          float* P = reinterpret_cast<float*>(Cout) + (size_t)blockIdx.z * M * N;
          P[(size_t)row * N + col] = v;
        } else {
          v += bias[col];
          float c1 = (float)comp[(size_t)row * N + col];
          float sg_ = c1 / (1.0f + __expf(-c1));
          reinterpret_cast<bf16_t*>(Cout)[(size_t)row * N + col] = (bf16_t)(sg_ * v);
        }
      }
    }
  }
}

// ---------------- combine split-K partials + bias + residual ---------------
__global__ void combine_kernel(const float* __restrict__ part,
                               const float* __restrict__ bias,
                               const float* __restrict__ res,
                               float* __restrict__ out, int n4) {
  const int slice = NTOK * DIM / 4;
  int i = blockIdx.x * blockDim.x + threadIdx.x;
  int stride = gridDim.x * blockDim.x;
  const float4* p = reinterpret_cast<const float4*>(part);
  const float4* r4 = reinterpret_cast<const float4*>(res);
  const float4* b4 = reinterpret_cast<const float4*>(bias);
  float4* o4 = reinterpret_cast<float4*>(out);
  for (; i < n4; i += stride) {
    float4 a = p[i], b = p[i + slice], c = p[i + 2 * slice], d = p[i + 3 * slice];
    float4 rr = r4[i];
    float4 bb = b4[i & 255];
    float4 o;
    o.x = a.x + b.x + c.x + d.x + bb.x + rr.x;
    o.y = a.y + b.y + c.y + d.y + bb.y + rr.y;
    o.z = a.z + b.z + c.z + d.z + bb.z + rr.z;
    o.w = a.w + b.w + c.w + d.w + bb.w + rr.w;
    o4[i] = o;
  }
}

// ---------------- GEMM 128x128 (m97-style), out-proj / fallback ------------
// OUT_MODE: 0 = fp32 + bias + res; 2 = fp32 partial (slice z)
template <int OUT_MODE>
__global__ __launch_bounds__(256) void gemm_bt(
    const bf16_t* __restrict__ A, const bf16_t* __restrict__ B,
    const float* __restrict__ bias, const float* __restrict__ res,
    void* __restrict__ Cout, int M, int N, int Kfull, int Klen) {
  __shared__ bf16_t As[128][32];
  __shared__ bf16_t Bs[128][32];
  const int nTn = N >> 7;
  const int nwg = gridDim.x;
  const int bid = blockIdx.x;
  const int swz = ((nwg & 7) == 0) ? ((bid & 7) * (nwg >> 3) + (bid >> 3)) : bid;
  const int bm = swz / nTn;
  const int bn = swz % nTn;
  const int k0base = blockIdx.z * Klen;
  const int tid  = threadIdx.x;
  const int wid  = tid >> 6;
  const int lane = tid & 63;
  const int wm = (wid >> 1) * 64, wn = (wid & 1) * 64;
  const int lr = lane & 15;
  const int gq = lane >> 4;
  const int sr = lane >> 2;
  const int sg = lane & 3;
  const int cS = ((sg ^ ((sr >> 1) & 3)) << 3);
  const int swg = ((gq ^ ((lr >> 1) & 3)) << 3);
  f32x4 acc[4][4] = {};
  const bf16_t* Ag0 = A + (size_t)(bm * 128 + wid * 16 + sr) * Kfull + k0base + cS;
  const bf16_t* Ag1 = Ag0 + (size_t)64 * Kfull;
  const bf16_t* Bg0 = B + (size_t)(bn * 128 + wid * 16 + sr) * Kfull + k0base + cS;
  const bf16_t* Bg1 = Bg0 + (size_t)64 * Kfull;
  bf16_t* ldsA0 = &As[wid * 16][0];
  bf16_t* ldsA1 = &As[64 + wid * 16][0];
  bf16_t* ldsB0 = &Bs[wid * 16][0];
  bf16_t* ldsB1 = &Bs[64 + wid * 16][0];
  for (int k0 = 0; k0 < Klen; k0 += 32) {
    __syncthreads();
    GLOAD16(Ag0 + k0, ldsA0);
    GLOAD16(Ag1 + k0, ldsA1);
    GLOAD16(Bg0 + k0, ldsB0);
    GLOAD16(Bg1 + k0, ldsB1);
    __syncthreads();
    bf16x8 af[4], bfr[4];
#pragma unroll
    for (int mi = 0; mi < 4; ++mi)
      af[mi] = *reinterpret_cast<const bf16x8*>(&As[wm + mi * 16 + lr][swg]);
#pragma unroll
    for (int ni = 0; ni < 4; ++ni)
      bfr[ni] = *reinterpret_cast<const bf16x8*>(&Bs[wn + ni * 16 + lr][swg]);
#pragma unroll
    for (int mi = 0; mi < 4; ++mi)
#pragma unroll
      for (int ni = 0; ni < 4; ++ni)
        acc[mi][ni] = __builtin_amdgcn_mfma_f32_16x16x32_bf16(af[mi], bfr[ni], acc[mi][ni], 0, 0, 0);
  }
  const int r0 = (lane >> 4) * 4;
#pragma unroll
  for (int mi = 0; mi < 4; ++mi) {
#pragma unroll
    for (int r = 0; r < 4; ++r) {
      int row = bm * 128 + wm + mi * 16 + r0 + r;
#pragma unroll
      for (int ni = 0; ni < 4; ++ni) {
        int col = bn * 128 + wn + ni * 16 + lr;
        float v = acc[mi][ni][r];
        if (OUT_MODE == 0) {
          v += bias[col] + res[(size_t)row * N + col];
          reinterpret_cast<float*>(Cout)[(size_t)row * N + col] = v;
        } else {
          float* P = reinterpret_cast<float*>(Cout) + (size_t)blockIdx.z * M * N;
          P[(size_t)row * N + col] = v;
        }
      }
    }
  }
}

// ---------------- QK-norm (full-dim LN) + RoPE + BHSD repack ---------------
// Q is pre-scaled by log2(e)/8 so attention computes p = 2^(s_raw) directly.
__global__ __launch_bounds__(256) void qknorm_rope_kernel(
    const bf16_t* __restrict__ qkv,
    const float* __restrict__ qg, const float* __restrict__ qb,
    const float* __restrict__ kg, const float* __restrict__ kb,
    const float* __restrict__ rc, const float* __restrict__ rs,
    bf16_t* __restrict__ q_r, bf16_t* __restrict__ k_r) {
  int t = blockIdx.x;
  int b = t >> 11, s = t & 2047;
  const bf16_t* p = qkv + (size_t)t * 3072;
  int i = threadIdx.x;
  bf16x4 qv = *reinterpret_cast<const bf16x4*>(p + i * 4);
  bf16x4 kv = *reinterpret_cast<const bf16x4*>(p + 1024 + i * 4);
  float q4[4], k4[4];
  float sq = 0.f, sq2 = 0.f, sk = 0.f, sk2 = 0.f;
#pragma unroll
  for (int j = 0; j < 4; ++j) {
    q4[j] = (float)qv[j]; k4[j] = (float)kv[j];
    sq += q4[j]; sq2 += q4[j] * q4[j];
    sk += k4[j]; sk2 += k4[j] * k4[j];
  }
#pragma unroll
  for (int off = 32; off > 0; off >>= 1) {
    sq  += __shfl_down(sq, off, 64);
    sq2 += __shfl_down(sq2, off, 64);
    sk  += __shfl_down(sk, off, 64);
    sk2 += __shfl_down(sk2, off, 64);
  }
  __shared__ float red[4][4];
  int wid = i >> 6, lane = i & 63;
  if (lane == 0) { red[0][wid] = sq; red[1][wid] = sq2; red[2][wid] = sk; red[3][wid] = sk2; }
  __syncthreads();
  float Sq  = red[0][0] + red[0][1] + red[0][2] + red[0][3];
  float Sq2 = red[1][0] + red[1][1] + red[1][2] + red[1][3];
  float Sk  = red[2][0] + red[2][1] + red[2][2] + red[2][3];
  float Sk2 = red[3][0] + red[3][1] + red[3][2] + red[3][3];
  float mq = Sq * (1.0f / DIM);
  float vq = Sq2 * (1.0f / DIM) - mq * mq;
  float rq = rsqrtf(vq + 1e-6f);
  float mk = Sk * (1.0f / DIM);
  float vk = Sk2 * (1.0f / DIM) - mk * mk;
  float rk = rsqrtf(vk + 1e-6f);
  const float QS = 0.18033688011f;   // log2(e)/8 folded into Q
#pragma unroll
  for (int j = 0; j < 4; ++j) {
    int d = i * 4 + j, h = d >> 6, hd = d & 63, dp = d ^ 32;
    float c  = rc[s * HD + hd];
    float sn = rs[s * HD + hd];
    float qn  = (q4[j] - mq) * rq * qg[d] + qb[d];
    float qpn = ((float)p[dp] - mq) * rq * qg[dp] + qb[dp];
    float qo  = qn * c + ((hd < 32) ? -qpn : qpn) * sn;
    float kn  = (k4[j] - mk) * rk * kg[d] + kb[d];
    float kpn = ((float)p[1024 + dp] - mk) * rk * kg[dp] + kb[dp];
    float ko  = kn * c + ((hd < 32) ? -kpn : kpn) * sn;
    size_t oi = ((size_t)(b * HEADS + h) * SEQ + s) * HD + hd;
    q_r[oi] = (bf16_t)(qo * QS);
    k_r[oi] = (bf16_t)ko;
  }
}

// ---------------- V transpose: qkv[b,s,2048+h*64+d] -> v_t[bh][d][s] -------
__global__ __launch_bounds__(256) void vtrans_kernel(
    const bf16_t* __restrict__ qkv, bf16_t* __restrict__ v_t) {
  __shared__ bf16_t T[64][72];
  const int st = blockIdx.x;
  const int bh = blockIdx.y;
  const int b = bh >> 4, h = bh & 15;
  const int tid = threadIdx.x;
  const int r = tid >> 2, c = (tid & 3) * 8;
  const bf16_t* src = qkv + (size_t)(b * SEQ + st * 64 + r) * 3072 + 2048 + h * 64;
  *reinterpret_cast<bf16x8*>(&T[r][c])      = *reinterpret_cast<const bf16x8*>(src + c);
  *reinterpret_cast<bf16x8*>(&T[r][c + 32]) = *reinterpret_cast<const bf16x8*>(src + c + 32);
  __syncthreads();
  bf16x8 o0, o1;
#pragma unroll
  for (int j = 0; j < 8; ++j) { o0[j] = T[c + j][r]; o1[j] = T[c + 32 + j][r]; }
  bf16_t* dst = v_t + ((size_t)bh * 64 + r) * SEQ + st * 64;
  *reinterpret_cast<bf16x8*>(dst + c)      = o0;
  *reinterpret_cast<bf16x8*>(dst + c + 32) = o1;
}

// ---------------- Flash attention: granule-major LDS + in-block K-split ----
__global__ __launch_bounds__(512, 2) void attn_kernel(
    const bf16_t* __restrict__ q_r, const bf16_t* __restrict__ k_r,
    const bf16_t* __restrict__ v_t, bf16_t* __restrict__ attn_out) {
  __shared__ __align__(16) char smem[69632];
  bf16_t* KsB = (bf16_t*)smem;
  bf16_t* VsB = (bf16_t*)(smem + 32768);
  float*  Xch = (float*)smem;
  const int bid = blockIdx.x;
  const int hh = bid & 31;
  const int qt = bid >> 5;
  const int bidx = hh >> 4, h = hh & 15;
  const int tid = threadIdx.x, wid = tid >> 6, lane = tid & 63;
  const int kh = wid >> 2, ww = wid & 3;
  const int lq = lane & 31, hi = lane >> 5;
  const int qA = qt * 256 + ww * 64 + lq;
  const int qB = qA + 32;
  const bf16_t* Qp = q_r + (size_t)hh * SEQ * HD;
  const bf16_t* Kp = k_r + (size_t)hh * SEQ * HD + (size_t)kh * 1024 * HD;
  const bf16_t* Vp = v_t + (size_t)hh * HD * SEQ + kh * 1024;
  bf16_t* Ks0 = KsB + kh * 2 * 4096;
  bf16_t* Vs0 = VsB + kh * 2 * 4096;
  bf16x8 qfA[4], qfB[4];
#pragma unroll
  for (int kdt = 0; kdt < 4; ++kdt) {
    qfA[kdt] = *reinterpret_cast<const bf16x8*>(Qp + (size_t)qA * HD + kdt * 16 + hi * 8);
    qfB[kdt] = *reinterpret_cast<const bf16x8*>(Qp + (size_t)qB * HD + kdt * 16 + hi * 8);
  }
  f32x16 oA0 = {}, oA1 = {}, oB0 = {}, oB1 = {};
  float lA = 0.f, lB = 0.f;
  const int kSrcA = lane * HD + ww * 8;
  const int kSrcB = lane * HD + (ww + 4) * 8;
  const int vSrcA = lane * SEQ + ww * 8;
  const int vSrcB = lane * SEQ + (ww + 4) * 8;
  const int ldsA = ww * 512;
  const int ldsB = 2048 + ww * 512;
  GLOAD16(Kp + kSrcA, &Ks0[ldsA]);
  GLOAD16(Kp + kSrcB, &Ks0[ldsB]);
  GLOAD16(Vp + vSrcA, &Vs0[ldsA]);
  GLOAD16(Vp + vSrcB, &Vs0[ldsB]);
  __syncthreads();
  const int NT = 1024 / 64;
  for (int kt = 0; kt < NT; ++kt) {
    const int cur = kt & 1, nxt = cur ^ 1;
    if (kt + 1 < NT) {
      GLOAD16(Kp + (kt + 1) * (64 * HD) + kSrcA, &Ks0[nxt * 4096 + ldsA]);
      GLOAD16(Kp + (kt + 1) * (64 * HD) + kSrcB, &Ks0[nxt * 4096 + ldsB]);
      GLOAD16(Vp + (kt + 1) * 64 + vSrcA, &Vs0[nxt * 4096 + ldsA]);
      GLOAD16(Vp + (kt + 1) * 64 + vSrcB, &Vs0[nxt * 4096 + ldsB]);
    }
    f32x16 sA0 = {}, sA1 = {}, sB0 = {}, sB1 = {};
#pragma unroll
    for (int kdt = 0; kdt < 4; ++kdt) {
      const int goff = cur * 4096 + (kdt * 2 + hi) * 512;
      bf16x8 kf0 = *reinterpret_cast<const bf16x8*>(&Ks0[goff + lq * 8]);
      bf16x8 kf1 = *reinterpret_cast<const bf16x8*>(&Ks0[goff + (lq + 32) * 8]);
      sA0 = __builtin_amdgcn_mfma_f32_32x32x16_bf16(kf0, qfA[kdt], sA0, 0, 0, 0);
      sA1 = __builtin_amdgcn_mfma_f32_32x32x16_bf16(kf1, qfA[kdt], sA1, 0, 0, 0);
      sB0 = __builtin_amdgcn_mfma_f32_32x32x16_bf16(kf0, qfB[kdt], sB0, 0, 0, 0);
      sB1 = __builtin_amdgcn_mfma_f32_32x32x16_bf16(kf1, qfB[kdt], sB1, 0, 0, 0);
    }
#pragma unroll
    for (int i = 0; i < 16; ++i) sA0[i] = __builtin_amdgcn_exp2f(sA0[i]);
#pragma unroll
    for (int i = 0; i < 16; ++i) sA1[i] = __builtin_amdgcn_exp2f(sA1[i]);
#pragma unroll
    for (int i = 0; i < 16; ++i) sB0[i] = __builtin_amdgcn_exp2f(sB0[i]);
#pragma unroll
    for (int i = 0; i < 16; ++i) sB1[i] = __builtin_amdgcn_exp2f(sB1[i]);
    {
      f32x16 t = sA0 + sA1;
      float a = ((t[0] + t[8]) + (t[4] + t[12])) + ((t[2] + t[10]) + (t[6] + t[14]));
      float b = ((t[1] + t[9]) + (t[5] + t[13])) + ((t[3] + t[11]) + (t[7] + t[15]));
      lA += a + b;
      f32x16 u = sB0 + sB1;
      float c = ((u[0] + u[8]) + (u[4] + u[12])) + ((u[2] + u[10]) + (u[6] + u[14]));
      float d = ((u[1] + u[9]) + (u[5] + u[13])) + ((u[3] + u[11]) + (u[7] + u[15]));
      lB += c + d;
    }
#pragma unroll
    for (int tt = 0; tt < 2; ++tt) {
#pragma unroll
      for (int ks = 0; ks < 2; ++ks) {
        const f32x16& pA = tt ? sA1 : sA0;
        const f32x16& pB = tt ? sB1 : sB0;
        unsigned a0, b0, c0, d0, a1, b1, c1, d1;
        if (ks == 0) {
          a0 = CVTPK(pA[0], pA[1]); b0 = CVTPK(pA[4], pA[5]);
          c0 = CVTPK(pA[2], pA[3]); d0 = CVTPK(pA[6], pA[7]);
          a1 = CVTPK(pB[0], pB[1]); b1 = CVTPK(pB[4], pB[5]);
          c1 = CVTPK(pB[2], pB[3]); d1 = CVTPK(pB[6], pB[7]);
        } else {
          a0 = CVTPK(pA[8], pA[9]);   b0 = CVTPK(pA[12], pA[13]);
          c0 = CVTPK(pA[10], pA[11]); d0 = CVTPK(pA[14], pA[15]);
          a1 = CVTPK(pB[8], pB[9]);   b1 = CVTPK(pB[12], pB[13]);
          c1 = CVTPK(pB[10], pB[11]); d1 = CVTPK(pB[14], pB[15]);
        }
        PLSWAP(a0, b0); PLSWAP(c0, d0); PLSWAP(a1, b1); PLSWAP(c1, d1);
        union { unsigned u[4]; bf16x8 v; } pfA, pfB;
        pfA.u[0] = a0; pfA.u[1] = c0; pfA.u[2] = b0; pfA.u[3] = d0;
        pfB.u[0] = a1; pfB.u[1] = c1; pfB.u[2] = b1; pfB.u[3] = d1;
        const int gv = cur * 4096 + (tt * 4 + ks * 2 + hi) * 512;
        bf16x8 vf0 = *reinterpret_cast<const bf16x8*>(&Vs0[gv + lq * 8]);
        bf16x8 vf1 = *reinterpret_cast<const bf16x8*>(&Vs0[gv + (lq + 32) * 8]);
        oA0 = __builtin_amdgcn_mfma_f32_32x32x16_bf16(vf0, pfA.v, oA0, 0, 0, 0);
        oA1 = __builtin_amdgcn_mfma_f32_32x32x16_bf16(vf1, pfA.v, oA1, 0, 0, 0);
        oB0 = __builtin_amdgcn_mfma_f32_32x32x16_bf16(vf0, pfB.v, oB0, 0, 0, 0);
        oB1 = __builtin_amdgcn_mfma_f32_32x32x16_bf16(vf1, pfB.v, oB1, 0, 0, 0);
      }
    }
    __syncthreads();
  }
  lA += __shfl_xor(lA, 32, 64);
  lB += __shfl_xor(lB, 32, 64);
  if (kh == 1) {
    float* my = Xch + (size_t)(ww * 64 + lane) * 68;
#pragma unroll
    for (int g = 0; g < 4; ++g) {
      *reinterpret_cast<float4*>(my + g * 4)      = make_float4(oA0[g*4], oA0[g*4+1], oA0[g*4+2], oA0[g*4+3]);
      *reinterpret_cast<float4*>(my + 16 + g * 4) = make_float4(oA1[g*4], oA1[g*4+1], oA1[g*4+2], oA1[g*4+3]);
      *reinterpret_cast<float4*>(my + 32 + g * 4) = make_float4(oB0[g*4], oB0[g*4+1], oB0[g*4+2], oB0[g*4+3]);
      *reinterpret_cast<float4*>(my + 48 + g * 4) = make_float4(oB1[g*4], oB1[g*4+1], oB1[g*4+2], oB1[g*4+3]);
    }
    my[64] = lA; my[65] = lB;
  }
  __syncthreads();
  if (kh == 0) {
    const float* pr = Xch + (size_t)(ww * 64 + lane) * 68;
#pragma unroll
    for (int i = 0; i < 16; ++i) {
      oA0[i] += pr[i];      oA1[i] += pr[16 + i];
      oB0[i] += pr[32 + i]; oB1[i] += pr[48 + i];
    }
    float invA = 1.0f / (lA + pr[64]);
    float invB = 1.0f / (lB + pr[65]);
    bf16_t* orowA = attn_out + ((size_t)(bidx * SEQ + qA)) * DIM + h * 64;
    bf16_t* orowB = attn_out + ((size_t)(bidx * SEQ + qB)) * DIM + h * 64;
#pragma unroll
    for (int g = 0; g < 4; ++g) {
      bf16x4 wA0, wA1, wB0, wB1;
#pragma unroll
      for (int j = 0; j < 4; ++j) {
        wA0[j] = (bf16_t)(oA0[g * 4 + j] * invA);
        wA1[j] = (bf16_t)(oA1[g * 4 + j] * invA);
        wB0[j] = (bf16_t)(oB0[g * 4 + j] * invB);
        wB1[j] = (bf16_t)(oB1[g * 4 + j] * invB);
      }
      *reinterpret_cast<bf16x4*>(orowA + g * 8 + 4 * hi)      = wA0;
      *reinterpret_cast<bf16x4*>(orowA + 32 + g * 8 + 4 * hi) = wA1;
      *reinterpret_cast<bf16x4*>(orowB + g * 8 + 4 * hi)      = wB0;
      *reinterpret_cast<bf16x4*>(orowB + 32 + g * 8 + 4 * hi) = wB1;
    }
  }
}

// ---------------------------------------------------------------------------
extern "C" void kernel_launch(void* const* d_in, const int* in_sizes, int n_in,
                              void* d_out, int out_size, void* d_ws, size_t ws_size,
                              hipStream_t stream) {
  const float* x        = (const float*)d_in[0];
  const float* rope_cos = (const float*)d_in[1];
  const float* rope_sin = (const float*)d_in[2];
  const float* w_qkv    = (const float*)d_in[3];
  const float* b_qkv    = (const float*)d_in[4];
  const float* w_out    = (const float*)d_in[5];
  const float* b_out    = (const float*)d_in[6];
  const float* qn_g     = (const float*)d_in[7];
  const float* qn_b     = (const float*)d_in[8];
  const float* kn_g     = (const float*)d_in[9];
  const float* kn_b     = (const float*)d_in[10];
  const float* ln1_g    = (const float*)d_in[11];
  const float* ln1_b    = (const float*)d_in[12];
  const float* ln2_g    = (const float*)d_in[13];
  const float* ln2_b    = (const float*)d_in[14];
  const float* w1       = (const float*)d_in[15];
  const float* b1       = (const float*)d_in[16];
  const float* w2       = (const float*)d_in[17];
  const float* b2       = (const float*)d_in[18];
  const float* w3       = (const float*)d_in[19];
  const float* b3       = (const float*)d_in[20];

  const size_t OFF_WQKV = 0;
  const size_t OFF_WOUT = 6291456;
  const size_t OFF_W1   = 8388608;
  const size_t OFF_W2   = 16777216;
  const size_t OFF_W3   = 25165824;
  const size_t OFF_H1   = 33554432;
  const size_t OFF_QKV  = 41943040;
  const size_t OFF_QR   = 67108864;
  const size_t OFF_KR   = 75497472;
  const size_t OFF_VT   = 83886080;
  const size_t OFF_ATT  = 92274688;
  const size_t OFF_X2   = 100663296;
  const size_t OFF_H2   = 117440512;
  const size_t OFF_A1   = 33554432;   // reuse h1+qkv (dead by FFN)
  const size_t OFF_A3   = 67108864;   // reuse q/k/vt/att (dead by FFN)
  const size_t OFF_PART = 125829120;  // 4 x 16MB fp32 split-K partials (w2)
  const size_t NEEDED   = 125829120;
  const size_t NEED_SPLIT = OFF_PART + 67108864;
  if (ws_size < NEEDED) return;
  const bool use_split = (ws_size >= NEED_SPLIT);

  char* ws = (char*)d_ws;
  bf16_t* wqkv_bf = (bf16_t*)(ws + OFF_WQKV);
  bf16_t* wout_bf = (bf16_t*)(ws + OFF_WOUT);
  bf16_t* w1_bf   = (bf16_t*)(ws + OFF_W1);
  bf16_t* w2_bf   = (bf16_t*)(ws + OFF_W2);
  bf16_t* w3_bf   = (bf16_t*)(ws + OFF_W3);
  bf16_t* h1      = (bf16_t*)(ws + OFF_H1);
  bf16_t* qkv     = (bf16_t*)(ws + OFF_QKV);
  bf16_t* q_r     = (bf16_t*)(ws + OFF_QR);
  bf16_t* k_r     = (bf16_t*)(ws + OFF_KR);
  bf16_t* v_t     = (bf16_t*)(ws + OFF_VT);
  bf16_t* att     = (bf16_t*)(ws + OFF_ATT);
  float*  x2      = (float*)(ws + OFF_X2);
  bf16_t* h2      = (bf16_t*)(ws + OFF_H2);
  bf16_t* a1      = (bf16_t*)(ws + OFF_A1);
  bf16_t* a3      = (bf16_t*)(ws + OFF_A3);
  float*  part    = (float*)(ws + OFF_PART);
  float*  out     = (float*)d_out;

  f2bf_all_kernel<<<2048, 256, 0, stream>>>(w_qkv, w_out, w1, w2, w3,
                                            wqkv_bf, wout_bf, w1_bf, w2_bf, w3_bf);
  ln_kernel<<<NTOK, 256, 0, stream>>>(x, ln1_g, ln1_b, h1);
  gemm256<1><<<dim3(192, 1, 1), 512, 0, stream>>>(h1, wqkv_bf, b_qkv, nullptr, qkv,
                                                  NTOK, 3072, DIM, DIM);
  qknorm_rope_kernel<<<NTOK, 256, 0, stream>>>(qkv, qn_g, qn_b, kn_g, kn_b,
                                               rope_cos, rope_sin, q_r, k_r);
  vtrans_kernel<<<dim3(SEQ / 64, NB * HEADS), 256, 0, stream>>>(qkv, v_t);
  attn_kernel<<<256, 512, 0, stream>>>(q_r, k_r, v_t, att);
  gemm_bt<0><<<dim3(32 * 8, 1, 1), 256, 0, stream>>>(
      att, wout_bf, b_out, x, x2, NTOK, DIM, DIM, DIM);
  ln_kernel<<<NTOK, 256, 0, stream>>>(x2, ln2_g, ln2_b, h2);
  gemm256<1><<<dim3(256, 1, 1), 512, 0, stream>>>(h2, w1_bf, b1, nullptr, a1,
                                                  NTOK, FFND, DIM, DIM);
  gemm256<3><<<dim3(256, 1, 1), 512, 0, stream>>>(h2, w3_bf, b3, a1, a3,
                                                  NTOK, FFND, DIM, DIM);
  if (use_split) {
    gemm256<2><<<dim3(64, 1, 4), 512, 0, stream>>>(a3, w2_bf, nullptr, nullptr, part,
                                                   NTOK, DIM, FFND, FFND / 4);
    combine_kernel<<<2048, 256, 0, stream>>>(part, b2, x2, out, NTOK * DIM / 4);
  } else {
    gemm_bt<0><<<dim3(32 * 8, 1, 1), 256, 0, stream>>>(
        a3, w2_bf, b2, x2, out, NTOK, DIM, FFND, FFND);
  }
}

// Round 13
// 336.147 us; speedup vs baseline: 4.0637x; 4.0637x over previous
//
#include <hip/hip_runtime.h>
#include <hip/hip_bf16.h>

// ---------------------------------------------------------------------------
// Transformer layer: LN1 -> QKV GEMM -> QKnorm+RoPE -> flash attn -> outproj
//                    (+res) -> LN2 -> SwiGLU FFN (+res)
// B=2 S=2048 DIM=1024 H=16 HD=64 FFN=4096. fp32 I/O, bf16 MFMA compute.
// R13: revert R12 spill disaster (launch_bounds(512,4) -> 64 VGPR cap ->
//      accumulator spill, 1.18GB scratch writes). Base = R11 (299us).
//      gemm256 v3: T4 counted vmcnt -- BK=32, THREE LDS buffers (96KB),
//      stage t+2 post-barrier, wait vmcnt(4) (tile t done, t+1 in flight;
//      never drain mid-loop -- m218's +38-73% lever, previously misapplied
//      as vmcnt(0) which drained the fresh loads every tile).
// ---------------------------------------------------------------------------

typedef __bf16 bf16_t;
typedef bf16_t bf16x8 __attribute__((ext_vector_type(8)));
typedef bf16_t bf16x4 __attribute__((ext_vector_type(4)));
typedef float  f32x4  __attribute__((ext_vector_type(4)));
typedef float  f32x16 __attribute__((ext_vector_type(16)));

#define DIM   1024
#define HEADS 16
#define HD    64
#define FFND  4096
#define NB    2
#define SEQ   2048
#define NTOK  (NB * SEQ)   // 4096

#define GLOAD16(gp, lp) __builtin_amdgcn_global_load_lds( \
    (const __attribute__((address_space(1))) void*)(gp),  \
    (__attribute__((address_space(3))) void*)(lp), 16, 0, 0)

#define CVTPK(lo, hi_) ({ unsigned r_;                                        \
  asm("v_cvt_pk_bf16_f32 %0, %1, %2" : "=v"(r_) : "v"(lo), "v"(hi_)); r_; })
#define PLSWAP(a, b) asm("v_permlane32_swap_b32 %0, %1" : "+v"(a), "+v"(b))
#define SBAR() asm volatile("s_barrier" ::: "memory")

// ---------------- fp32 -> bf16 convert, all 5 weights in one launch --------
#define F2B_S0 786432
#define F2B_S1 262144
#define F2B_S2 1048576
#define F2B_S3 1048576
#define F2B_S4 1048576
#define F2B_C1 (F2B_S0)
#define F2B_C2 (F2B_C1 + F2B_S1)
#define F2B_C3 (F2B_C2 + F2B_S2)
#define F2B_C4 (F2B_C3 + F2B_S3)
#define F2B_N  (F2B_C4 + F2B_S4)

__global__ void f2bf_all_kernel(const float* __restrict__ s0, const float* __restrict__ s1,
                                const float* __restrict__ s2, const float* __restrict__ s3,
                                const float* __restrict__ s4,
                                bf16_t* __restrict__ d0, bf16_t* __restrict__ d1,
                                bf16_t* __restrict__ d2, bf16_t* __restrict__ d3,
                                bf16_t* __restrict__ d4) {
  int idx = blockIdx.x * blockDim.x + threadIdx.x;
  int stride = gridDim.x * blockDim.x;
  for (; idx < F2B_N; idx += stride) {
    const float* src; bf16_t* dst; int i;
    if (idx < F2B_C1)      { src = s0; dst = d0; i = idx; }
    else if (idx < F2B_C2) { src = s1; dst = d1; i = idx - F2B_C1; }
    else if (idx < F2B_C3) { src = s2; dst = d2; i = idx - F2B_C2; }
    else if (idx < F2B_C4) { src = s3; dst = d3; i = idx - F2B_C3; }
    else                   { src = s4; dst = d4; i = idx - F2B_C4; }
    float4 v = reinterpret_cast<const float4*>(src)[i];
    bf16x4 o;
    o[0] = (bf16_t)v.x; o[1] = (bf16_t)v.y; o[2] = (bf16_t)v.z; o[3] = (bf16_t)v.w;
    reinterpret_cast<bf16x4*>(dst)[i] = o;
  }
}

// ---------------- LayerNorm (one token per block, 256 thr) ----------------
__global__ __launch_bounds__(256) void ln_kernel(
    const float* __restrict__ x, const float* __restrict__ g,
    const float* __restrict__ b, bf16_t* __restrict__ out) {
  int t = blockIdx.x;
  int i = threadIdx.x;
  float4 v = reinterpret_cast<const float4*>(x + (size_t)t * DIM)[i];
  float s  = v.x + v.y + v.z + v.w;
  float s2 = v.x * v.x + v.y * v.y + v.z * v.z + v.w * v.w;
#pragma unroll
  for (int off = 32; off > 0; off >>= 1) {
    s  += __shfl_down(s, off, 64);
    s2 += __shfl_down(s2, off, 64);
  }
  __shared__ float red[2][4];
  int wid = i >> 6, lane = i & 63;
  if (lane == 0) { red[0][wid] = s; red[1][wid] = s2; }
  __syncthreads();
  float S  = red[0][0] + red[0][1] + red[0][2] + red[0][3];
  float S2 = red[1][0] + red[1][1] + red[1][2] + red[1][3];
  float mean = S * (1.0f / DIM);
  float var  = S2 * (1.0f / DIM) - mean * mean;
  float r = rsqrtf(var + 1e-6f);
  float vv[4] = {v.x, v.y, v.z, v.w};
  bf16x4 o;
#pragma unroll
  for (int j = 0; j < 4; ++j) {
    int d = i * 4 + j;
    o[j] = (bf16_t)((vv[j] - mean) * r * g[d] + b[d]);
  }
  *reinterpret_cast<bf16x4*>(out + (size_t)t * DIM + i * 4) = o;
}

// ---------------- gemm256 v3: 256x256 tile, BK=32, 3-buffer counted vmcnt --
// OUT_MODE: 1 = bf16 + bias; 2 = fp32 partial (slice blockIdx.z, no bias);
//           3 = bf16 silu(comp)*(acc+bias)  [SwiGLU fused w3 epilogue]
// Pipeline: tiles t, t+1, t+2 resident in 3 LDS buffers. Per tile:
//   wait vmcnt(4)  [tile t's 4 loads done; t+1's 4 STAY IN FLIGHT]
//   s_barrier      [t visible to all; t-1 reads consumed]
//   stage t+2 (4 gload_lds/thread) into buf (t+2)%3
//   12 ds_read_b128 + 32 MFMA, compiler-interleaved.
// Never drains vmcnt to 0 mid-loop (T4 / m218).
template <int OUT_MODE>
__global__ __launch_bounds__(512, 2) void gemm256(
    const bf16_t* __restrict__ A, const bf16_t* __restrict__ B,
    const float* __restrict__ bias, const bf16_t* __restrict__ comp,
    void* __restrict__ Cout, int M, int N, int Kfull, int Klen) {
  __shared__ __align__(16) bf16_t Al[3][256][32];
  __shared__ __align__(16) bf16_t Bl[3][256][32];
  const int nTn = N >> 8;
  const int nwg = gridDim.x;
  const int bid = blockIdx.x;
  const int swz = ((nwg & 7) == 0) ? ((bid & 7) * (nwg >> 3) + (bid >> 3)) : bid;
  const int bm = swz / nTn, bn = swz % nTn;
  const int k0base = blockIdx.z * Klen;
  const int NT = Klen >> 5;                      // BK = 32
  const int tid = threadIdx.x, wid = tid >> 6, lane = tid & 63;
  const int wm2 = wid >> 2, wn = wid & 3;        // 2 x 4 waves
  const int lr = lane & 15, lg = lane >> 4;
  // staging: wave w covers rows w*16..w*16+15 of each 128-row half.
  const int sr4 = lane >> 2;                     // row within 16-row segment
  const int sg  = lane & 3;                      // dest granule
  const int cS  = ((sg ^ ((sr4 >> 1) & 3)) << 3);  // pre-swizzled src col
  const int swg = ((lg ^ ((lr >> 1) & 3)) << 3);   // swizzled read col
  const bf16_t* Abase = A + (size_t)(bm * 256 + wid * 16 + sr4) * Kfull + k0base + cS;
  const bf16_t* Bbase = B + (size_t)(bn * 256 + wid * 16 + sr4) * Kfull + k0base + cS;

#define STAGE_A(buf, h, t)                                                    \
  GLOAD16(Abase + (size_t)(h) * 128 * Kfull + (size_t)(t) * 32,               \
          &Al[buf][(h) * 128 + wid * 16][0])
#define STAGE_B(buf, h, t)                                                    \
  GLOAD16(Bbase + (size_t)(h) * 128 * Kfull + (size_t)(t) * 32,               \
          &Bl[buf][(h) * 128 + wid * 16][0])
#define STAGE_TILE(buf, t) do {                                               \
    STAGE_A(buf, 0, t); STAGE_A(buf, 1, t);                                   \
    STAGE_B(buf, 0, t); STAGE_B(buf, 1, t); } while (0)

  f32x4 acc[8][4] = {};
  // prologue: tiles 0 and 1 in flight (8 loads/thread outstanding)
  STAGE_TILE(0, 0);
  if (NT > 1) STAGE_TILE(1, 1);

  for (int t = 0; t < NT; ++t) {
    const int bufc = t % 3;
    if (t + 1 < NT) {
      asm volatile("s_waitcnt vmcnt(4)" ::: "memory");  // t done; t+1 in flight
    } else {
      asm volatile("s_waitcnt vmcnt(0)" ::: "memory");  // last tile: drain
    }
    SBAR();                                             // t visible; t-1 reads consumed
    if (t + 2 < NT) STAGE_TILE((t + 2) % 3, t + 2);     // overwrites buf (t-1)%3
    bf16x8 af[8], bfr[4];
#pragma unroll
    for (int nf = 0; nf < 4; ++nf) {
      const int row = wn * 64 + nf * 16 + lr;
      bfr[nf] = *reinterpret_cast<const bf16x8*>(&Bl[bufc][row][swg]);
    }
#pragma unroll
    for (int mf = 0; mf < 8; ++mf) {
      const int row = wm2 * 128 + mf * 16 + lr;
      af[mf] = *reinterpret_cast<const bf16x8*>(&Al[bufc][row][swg]);
    }
    __builtin_amdgcn_s_setprio(1);
#pragma unroll
    for (int mf = 0; mf < 8; ++mf)
#pragma unroll
      for (int nf = 0; nf < 4; ++nf)
        acc[mf][nf] = __builtin_amdgcn_mfma_f32_16x16x32_bf16(af[mf], bfr[nf], acc[mf][nf], 0, 0, 0);
    __builtin_amdgcn_s_setprio(0);
  }
#undef STAGE_A
#undef STAGE_B
#undef STAGE_TILE
  const int r0 = lg * 4;
#pragma unroll
  for (int mf = 0; mf < 8; ++mf) {
#pragma unroll
    for (int r = 0; r < 4; ++r) {
      const int row = bm * 256 + wm2 * 128 + mf * 16 + r0 + r;
#pragma unroll
      for (int nf = 0; nf < 4; ++nf) {
        const int col = bn * 256 + wn * 64 + nf * 16 + lr;
        float v = acc[mf][nf][r];
        if (OUT_MODE == 1) {
          v += bias[col];
          reinterpret_cast<bf16_t*>(Cout)[(size_t)row * N + col] = (bf16_t)v;
        } else if (OUT_MODE == 2) {
          float* P = reinterpret_cast<float*>(Cout) + (size_t)blockIdx.z * M * N;
          P[(size_t)row * N + col] = v;
        } else {
          v += bias[col];
          float c1 = (float)comp[(size_t)row * N + col];
          float sg_ = c1 / (1.0f + __expf(-c1));
          reinterpret_cast<bf16_t*>(Cout)[(size_t)row * N + col] = (bf16_t)(sg_ * v);
        }
      }
    }
  }
}

// ---------------- combine split-K partials + bias + residual ---------------
__global__ void combine_kernel(const float* __restrict__ part,
                               const float* __restrict__ bias,
                               const float* __restrict__ res,
                               float* __restrict__ out, int n4) {
  const int slice = NTOK * DIM / 4;
  int i = blockIdx.x * blockDim.x + threadIdx.x;
  int stride = gridDim.x * blockDim.x;
  const float4* p = reinterpret_cast<const float4*>(part);
  const float4* r4 = reinterpret_cast<const float4*>(res);
  const float4* b4 = reinterpret_cast<const float4*>(bias);
  float4* o4 = reinterpret_cast<float4*>(out);
  for (; i < n4; i += stride) {
    float4 a = p[i], b = p[i + slice], c = p[i + 2 * slice], d = p[i + 3 * slice];
    float4 rr = r4[i];
    float4 bb = b4[i & 255];
    float4 o;
    o.x = a.x + b.x + c.x + d.x + bb.x + rr.x;
    o.y = a.y + b.y + c.y + d.y + bb.y + rr.y;
    o.z = a.z + b.z + c.z + d.z + bb.z + rr.z;
    o.w = a.w + b.w + c.w + d.w + bb.w + rr.w;
    o4[i] = o;
  }
}

// ---------------- GEMM 128x128 (m97-style), out-proj / fallback ------------
// OUT_MODE: 0 = fp32 + bias + res; 2 = fp32 partial (slice z)
template <int OUT_MODE>
__global__ __launch_bounds__(256) void gemm_bt(
    const bf16_t* __restrict__ A, const bf16_t* __restrict__ B,
    const float* __restrict__ bias, const float* __restrict__ res,
    void* __restrict__ Cout, int M, int N, int Kfull, int Klen) {
  __shared__ bf16_t As[128][32];
  __shared__ bf16_t Bs[128][32];
  const int nTn = N >> 7;
  const int nwg = gridDim.x;
  const int bid = blockIdx.x;
  const int swz = ((nwg & 7) == 0) ? ((bid & 7) * (nwg >> 3) + (bid >> 3)) : bid;
  const int bm = swz / nTn;
  const int bn = swz % nTn;
  const int k0base = blockIdx.z * Klen;
  const int tid  = threadIdx.x;
  const int wid  = tid >> 6;
  const int lane = tid & 63;
  const int wm = (wid >> 1) * 64, wn = (wid & 1) * 64;
  const int lr = lane & 15;
  const int gq = lane >> 4;
  const int sr = lane >> 2;
  const int sg = lane & 3;
  const int cS = ((sg ^ ((sr >> 1) & 3)) << 3);
  const int swg = ((gq ^ ((lr >> 1) & 3)) << 3);
  f32x4 acc[4][4] = {};
  const bf16_t* Ag0 = A + (size_t)(bm * 128 + wid * 16 + sr) * Kfull + k0base + cS;
  const bf16_t* Ag1 = Ag0 + (size_t)64 * Kfull;
  const bf16_t* Bg0 = B + (size_t)(bn * 128 + wid * 16 + sr) * Kfull + k0base + cS;
  const bf16_t* Bg1 = Bg0 + (size_t)64 * Kfull;
  bf16_t* ldsA0 = &As[wid * 16][0];
  bf16_t* ldsA1 = &As[64 + wid * 16][0];
  bf16_t* ldsB0 = &Bs[wid * 16][0];
  bf16_t* ldsB1 = &Bs[64 + wid * 16][0];
  for (int k0 = 0; k0 < Klen; k0 += 32) {
    __syncthreads();
    GLOAD16(Ag0 + k0, ldsA0);
    GLOAD16(Ag1 + k0, ldsA1);
    GLOAD16(Bg0 + k0, ldsB0);
    GLOAD16(Bg1 + k0, ldsB1);
    __syncthreads();
    bf16x8 af[4], bfr[4];
#pragma unroll
    for (int mi = 0; mi < 4; ++mi)
      af[mi] = *reinterpret_cast<const bf16x8*>(&As[wm + mi * 16 + lr][swg]);
#pragma unroll
    for (int ni = 0; ni < 4; ++ni)
      bfr[ni] = *reinterpret_cast<const bf16x8*>(&Bs[wn + ni * 16 + lr][swg]);
#pragma unroll
    for (int mi = 0; mi < 4; ++mi)
#pragma unroll
      for (int ni = 0; ni < 4; ++ni)
        acc[mi][ni] = __builtin_amdgcn_mfma_f32_16x16x32_bf16(af[mi], bfr[ni], acc[mi][ni], 0, 0, 0);
  }
  const int r0 = (lane >> 4) * 4;
#pragma unroll
  for (int mi = 0; mi < 4; ++mi) {
#pragma unroll
    for (int r = 0; r < 4; ++r) {
      int row = bm * 128 + wm + mi * 16 + r0 + r;
#pragma unroll
      for (int ni = 0; ni < 4; ++ni) {
        int col = bn * 128 + wn + ni * 16 + lr;
        float v = acc[mi][ni][r];
        if (OUT_MODE == 0) {
          v += bias[col] + res[(size_t)row * N + col];
          reinterpret_cast<float*>(Cout)[(size_t)row * N + col] = v;
        } else {
          float* P = reinterpret_cast<float*>(Cout) + (size_t)blockIdx.z * M * N;
          P[(size_t)row * N + col] = v;
        }
      }
    }
  }
}

// ---------------- QK-norm (full-dim LN) + RoPE + BHSD repack ---------------
// Q is pre-scaled by log2(e)/8 so attention computes p = 2^(s_raw) directly.
__global__ __launch_bounds__(256) void qknorm_rope_kernel(
    const bf16_t* __restrict__ qkv,
    const float* __restrict__ qg, const float* __restrict__ qb,
    const float* __restrict__ kg, const float* __restrict__ kb,
    const float* __restrict__ rc, const float* __restrict__ rs,
    bf16_t* __restrict__ q_r, bf16_t* __restrict__ k_r) {
  int t = blockIdx.x;
  int b = t >> 11, s = t & 2047;
  const bf16_t* p = qkv + (size_t)t * 3072;
  int i = threadIdx.x;
  bf16x4 qv = *reinterpret_cast<const bf16x4*>(p + i * 4);
  bf16x4 kv = *reinterpret_cast<const bf16x4*>(p + 1024 + i * 4);
  float q4[4], k4[4];
  float sq = 0.f, sq2 = 0.f, sk = 0.f, sk2 = 0.f;
#pragma unroll
  for (int j = 0; j < 4; ++j) {
    q4[j] = (float)qv[j]; k4[j] = (float)kv[j];
    sq += q4[j]; sq2 += q4[j] * q4[j];
    sk += k4[j]; sk2 += k4[j] * k4[j];
  }
#pragma unroll
  for (int off = 32; off > 0; off >>= 1) {
    sq  += __shfl_down(sq, off, 64);
    sq2 += __shfl_down(sq2, off, 64);
    sk  += __shfl_down(sk, off, 64);
    sk2 += __shfl_down(sk2, off, 64);
  }
  __shared__ float red[4][4];
  int wid = i >> 6, lane = i & 63;
  if (lane == 0) { red[0][wid] = sq; red[1][wid] = sq2; red[2][wid] = sk; red[3][wid] = sk2; }
  __syncthreads();
  float Sq  = red[0][0] + red[0][1] + red[0][2] + red[0][3];
  float Sq2 = red[1][0] + red[1][1] + red[1][2] + red[1][3];
  float Sk  = red[2][0] + red[2][1] + red[2][2] + red[2][3];
  float Sk2 = red[3][0] + red[3][1] + red[3][2] + red[3][3];
  float mq = Sq * (1.0f / DIM);
  float vq = Sq2 * (1.0f / DIM) - mq * mq;
  float rq = rsqrtf(vq + 1e-6f);
  float mk = Sk * (1.0f / DIM);
  float vk = Sk2 * (1.0f / DIM) - mk * mk;
  float rk = rsqrtf(vk + 1e-6f);
  const float QS = 0.18033688011f;   // log2(e)/8 folded into Q
#pragma unroll
  for (int j = 0; j < 4; ++j) {
    int d = i * 4 + j, h = d >> 6, hd = d & 63, dp = d ^ 32;
    float c  = rc[s * HD + hd];
    float sn = rs[s * HD + hd];
    float qn  = (q4[j] - mq) * rq * qg[d] + qb[d];
    float qpn = ((float)p[dp] - mq) * rq * qg[dp] + qb[dp];
    float qo  = qn * c + ((hd < 32) ? -qpn : qpn) * sn;
    float kn  = (k4[j] - mk) * rk * kg[d] + kb[d];
    float kpn = ((float)p[1024 + dp] - mk) * rk * kg[dp] + kb[dp];
    float ko  = kn * c + ((hd < 32) ? -kpn : kpn) * sn;
    size_t oi = ((size_t)(b * HEADS + h) * SEQ + s) * HD + hd;
    q_r[oi] = (bf16_t)(qo * QS);
    k_r[oi] = (bf16_t)ko;
  }
}

// ---------------- V transpose: qkv[b,s,2048+h*64+d] -> v_t[bh][d][s] -------
__global__ __launch_bounds__(256) void vtrans_kernel(
    const bf16_t* __restrict__ qkv, bf16_t* __restrict__ v_t) {
  __shared__ bf16_t T[64][72];
  const int st = blockIdx.x;
  const int bh = blockIdx.y;
  const int b = bh >> 4, h = bh & 15;
  const int tid = threadIdx.x;
  const int r = tid >> 2, c = (tid & 3) * 8;
  const bf16_t* src = qkv + (size_t)(b * SEQ + st * 64 + r) * 3072 + 2048 + h * 64;
  *reinterpret_cast<bf16x8*>(&T[r][c])      = *reinterpret_cast<const bf16x8*>(src + c);
  *reinterpret_cast<bf16x8*>(&T[r][c + 32]) = *reinterpret_cast<const bf16x8*>(src + c + 32);
  __syncthreads();
  bf16x8 o0, o1;
#pragma unroll
  for (int j = 0; j < 8; ++j) { o0[j] = T[c + j][r]; o1[j] = T[c + 32 + j][r]; }
  bf16_t* dst = v_t + ((size_t)bh * 64 + r) * SEQ + st * 64;
  *reinterpret_cast<bf16x8*>(dst + c)      = o0;
  *reinterpret_cast<bf16x8*>(dst + c + 32) = o1;
}

// ---------------- Flash attention: granule-major LDS + in-block K-split ----
__global__ __launch_bounds__(512, 2) void attn_kernel(
    const bf16_t* __restrict__ q_r, const bf16_t* __restrict__ k_r,
    const bf16_t* __restrict__ v_t, bf16_t* __restrict__ attn_out) {
  __shared__ __align__(16) char smem[69632];
  bf16_t* KsB = (bf16_t*)smem;
  bf16_t* VsB = (bf16_t*)(smem + 32768);
  float*  Xch = (float*)smem;
  const int bid = blockIdx.x;
  const int hh = bid & 31;
  const int qt = bid >> 5;
  const int bidx = hh >> 4, h = hh & 15;
  const int tid = threadIdx.x, wid = tid >> 6, lane = tid & 63;
  const int kh = wid >> 2, ww = wid & 3;
  const int lq = lane & 31, hi = lane >> 5;
  const int qA = qt * 256 + ww * 64 + lq;
  const int qB = qA + 32;
  const bf16_t* Qp = q_r + (size_t)hh * SEQ * HD;
  const bf16_t* Kp = k_r + (size_t)hh * SEQ * HD + (size_t)kh * 1024 * HD;
  const bf16_t* Vp = v_t + (size_t)hh * HD * SEQ + kh * 1024;
  bf16_t* Ks0 = KsB + kh * 2 * 4096;
  bf16_t* Vs0 = VsB + kh * 2 * 4096;
  bf16x8 qfA[4], qfB[4];
#pragma unroll
  for (int kdt = 0; kdt < 4; ++kdt) {
    qfA[kdt] = *reinterpret_cast<const bf16x8*>(Qp + (size_t)qA * HD + kdt * 16 + hi * 8);
    qfB[kdt] = *reinterpret_cast<const bf16x8*>(Qp + (size_t)qB * HD + kdt * 16 + hi * 8);
  }
  f32x16 oA0 = {}, oA1 = {}, oB0 = {}, oB1 = {};
  float lA = 0.f, lB = 0.f;
  const int kSrcA = lane * HD + ww * 8;
  const int kSrcB = lane * HD + (ww + 4) * 8;
  const int vSrcA = lane * SEQ + ww * 8;
  const int vSrcB = lane * SEQ + (ww + 4) * 8;
  const int ldsA = ww * 512;
  const int ldsB = 2048 + ww * 512;
  GLOAD16(Kp + kSrcA, &Ks0[ldsA]);
  GLOAD16(Kp + kSrcB, &Ks0[ldsB]);
  GLOAD16(Vp + vSrcA, &Vs0[ldsA]);
  GLOAD16(Vp + vSrcB, &Vs0[ldsB]);
  __syncthreads();
  const int NT = 1024 / 64;
  for (int kt = 0; kt < NT; ++kt) {
    const int cur = kt & 1, nxt = cur ^ 1;
    if (kt + 1 < NT) {
      GLOAD16(Kp + (kt + 1) * (64 * HD) + kSrcA, &Ks0[nxt * 4096 + ldsA]);
      GLOAD16(Kp + (kt + 1) * (64 * HD) + kSrcB, &Ks0[nxt * 4096 + ldsB]);
      GLOAD16(Vp + (kt + 1) * 64 + vSrcA, &Vs0[nxt * 4096 + ldsA]);
      GLOAD16(Vp + (kt + 1) * 64 + vSrcB, &Vs0[nxt * 4096 + ldsB]);
    }
    f32x16 sA0 = {}, sA1 = {}, sB0 = {}, sB1 = {};
#pragma unroll
    for (int kdt = 0; kdt < 4; ++kdt) {
      const int goff = cur * 4096 + (kdt * 2 + hi) * 512;
      bf16x8 kf0 = *reinterpret_cast<const bf16x8*>(&Ks0[goff + lq * 8]);
      bf16x8 kf1 = *reinterpret_cast<const bf16x8*>(&Ks0[goff + (lq + 32) * 8]);
      sA0 = __builtin_amdgcn_mfma_f32_32x32x16_bf16(kf0, qfA[kdt], sA0, 0, 0, 0);
      sA1 = __builtin_amdgcn_mfma_f32_32x32x16_bf16(kf1, qfA[kdt], sA1, 0, 0, 0);
      sB0 = __builtin_amdgcn_mfma_f32_32x32x16_bf16(kf0, qfB[kdt], sB0, 0, 0, 0);
      sB1 = __builtin_amdgcn_mfma_f32_32x32x16_bf16(kf1, qfB[kdt], sB1, 0, 0, 0);
    }
#pragma unroll
    for (int i = 0; i < 16; ++i) sA0[i] = __builtin_amdgcn_exp2f(sA0[i]);
#pragma unroll
    for (int i = 0; i < 16; ++i) sA1[i] = __builtin_amdgcn_exp2f(sA1[i]);
#pragma unroll
    for (int i = 0; i < 16; ++i) sB0[i] = __builtin_amdgcn_exp2f(sB0[i]);
#pragma unroll
    for (int i = 0; i < 16; ++i) sB1[i] = __builtin_amdgcn_exp2f(sB1[i]);
    {
      f32x16 t = sA0 + sA1;
      float a = ((t[0] + t[8]) + (t[4] + t[12])) + ((t[2] + t[10]) + (t[6] + t[14]));
      float b = ((t[1] + t[9]) + (t[5] + t[13])) + ((t[3] + t[11]) + (t[7] + t[15]));
      lA += a + b;
      f32x16 u = sB0 + sB1;
      float c = ((u[0] + u[8]) + (u[4] + u[12])) + ((u[2] + u[10]) + (u[6] + u[14]));
      float d = ((u[1] + u[9]) + (u[5] + u[13])) + ((u[3] + u[11]) + (u[7] + u[15]));
      lB += c + d;
    }
#pragma unroll
    for (int tt = 0; tt < 2; ++tt) {
#pragma unroll
      for (int ks = 0; ks < 2; ++ks) {
        const f32x16& pA = tt ? sA1 : sA0;
        const f32x16& pB = tt ? sB1 : sB0;
        unsigned a0, b0, c0, d0, a1, b1, c1, d1;
        if (ks == 0) {
          a0 = CVTPK(pA[0], pA[1]); b0 = CVTPK(pA[4], pA[5]);
          c0 = CVTPK(pA[2], pA[3]); d0 = CVTPK(pA[6], pA[7]);
          a1 = CVTPK(pB[0], pB[1]); b1 = CVTPK(pB[4], pB[5]);
          c1 = CVTPK(pB[2], pB[3]); d1 = CVTPK(pB[6], pB[7]);
        } else {
          a0 = CVTPK(pA[8], pA[9]);   b0 = CVTPK(pA[12], pA[13]);
          c0 = CVTPK(pA[10], pA[11]); d0 = CVTPK(pA[14], pA[15]);
          a1 = CVTPK(pB[8], pB[9]);   b1 = CVTPK(pB[12], pB[13]);
          c1 = CVTPK(pB[10], pB[11]); d1 = CVTPK(pB[14], pB[15]);
        }
        PLSWAP(a0, b0); PLSWAP(c0, d0); PLSWAP(a1, b1); PLSWAP(c1, d1);
        union { unsigned u[4]; bf16x8 v; } pfA, pfB;
        pfA.u[0] = a0; pfA.u[1] = c0; pfA.u[2] = b0; pfA.u[3] = d0;
        pfB.u[0] = a1; pfB.u[1] = c1; pfB.u[2] = b1; pfB.u[3] = d1;
        const int gv = cur * 4096 + (tt * 4 + ks * 2 + hi) * 512;
        bf16x8 vf0 = *reinterpret_cast<const bf16x8*>(&Vs0[gv + lq * 8]);
        bf16x8 vf1 = *reinterpret_cast<const bf16x8*>(&Vs0[gv + (lq + 32) * 8]);
        oA0 = __builtin_amdgcn_mfma_f32_32x32x16_bf16(vf0, pfA.v, oA0, 0, 0, 0);
        oA1 = __builtin_amdgcn_mfma_f32_32x32x16_bf16(vf1, pfA.v, oA1, 0, 0, 0);
        oB0 = __builtin_amdgcn_mfma_f32_32x32x16_bf16(vf0, pfB.v, oB0, 0, 0, 0);
        oB1 = __builtin_amdgcn_mfma_f32_32x32x16_bf16(vf1, pfB.v, oB1, 0, 0, 0);
      }
    }
    __syncthreads();
  }
  lA += __shfl_xor(lA, 32, 64);
  lB += __shfl_xor(lB, 32, 64);
  if (kh == 1) {
    float* my = Xch + (size_t)(ww * 64 + lane) * 68;
#pragma unroll
    for (int g = 0; g < 4; ++g) {
      *reinterpret_cast<float4*>(my + g * 4)      = make_float4(oA0[g*4], oA0[g*4+1], oA0[g*4+2], oA0[g*4+3]);
      *reinterpret_cast<float4*>(my + 16 + g * 4) = make_float4(oA1[g*4], oA1[g*4+1], oA1[g*4+2], oA1[g*4+3]);
      *reinterpret_cast<float4*>(my + 32 + g * 4) = make_float4(oB0[g*4], oB0[g*4+1], oB0[g*4+2], oB0[g*4+3]);
      *reinterpret_cast<float4*>(my + 48 + g * 4) = make_float4(oB1[g*4], oB1[g*4+1], oB1[g*4+2], oB1[g*4+3]);
    }
    my[64] = lA; my[65] = lB;
  }
  __syncthreads();
  if (kh == 0) {
    const float* pr = Xch + (size_t)(ww * 64 + lane) * 68;
#pragma unroll
    for (int i = 0; i < 16; ++i) {
      oA0[i] += pr[i];      oA1[i] += pr[16 + i];
      oB0[i] += pr[32 + i]; oB1[i] += pr[48 + i];
    }
    float invA = 1.0f / (lA + pr[64]);
    float invB = 1.0f / (lB + pr[65]);
    bf16_t* orowA = attn_out + ((size_t)(bidx * SEQ + qA)) * DIM + h * 64;
    bf16_t* orowB = attn_out + ((size_t)(bidx * SEQ + qB)) * DIM + h * 64;
#pragma unroll
    for (int g = 0; g < 4; ++g) {
      bf16x4 wA0, wA1, wB0, wB1;
#pragma unroll
      for (int j = 0; j < 4; ++j) {
        wA0[j] = (bf16_t)(oA0[g * 4 + j] * invA);
        wA1[j] = (bf16_t)(oA1[g * 4 + j] * invA);
        wB0[j] = (bf16_t)(oB0[g * 4 + j] * invB);
        wB1[j] = (bf16_t)(oB1[g * 4 + j] * invB);
      }
      *reinterpret_cast<bf16x4*>(orowA + g * 8 + 4 * hi)      = wA0;
      *reinterpret_cast<bf16x4*>(orowA + 32 + g * 8 + 4 * hi) = wA1;
      *reinterpret_cast<bf16x4*>(orowB + g * 8 + 4 * hi)      = wB0;
      *reinterpret_cast<bf16x4*>(orowB + 32 + g * 8 + 4 * hi) = wB1;
    }
  }
}

// ---------------------------------------------------------------------------
extern "C" void kernel_launch(void* const* d_in, const int* in_sizes, int n_in,
                              void* d_out, int out_size, void* d_ws, size_t ws_size,
                              hipStream_t stream) {
  const float* x        = (const float*)d_in[0];
  const float* rope_cos = (const float*)d_in[1];
  const float* rope_sin = (const float*)d_in[2];
  const float* w_qkv    = (const float*)d_in[3];
  const float* b_qkv    = (const float*)d_in[4];
  const float* w_out    = (const float*)d_in[5];
  const float* b_out    = (const float*)d_in[6];
  const float* qn_g     = (const float*)d_in[7];
  const float* qn_b     = (const float*)d_in[8];
  const float* kn_g     = (const float*)d_in[9];
  const float* kn_b     = (const float*)d_in[10];
  const float* ln1_g    = (const float*)d_in[11];
  const float* ln1_b    = (const float*)d_in[12];
  const float* ln2_g    = (const float*)d_in[13];
  const float* ln2_b    = (const float*)d_in[14];
  const float* w1       = (const float*)d_in[15];
  const float* b1       = (const float*)d_in[16];
  const float* w2       = (const float*)d_in[17];
  const float* b2       = (const float*)d_in[18];
  const float* w3       = (const float*)d_in[19];
  const float* b3       = (const float*)d_in[20];

  const size_t OFF_WQKV = 0;
  const size_t OFF_WOUT = 6291456;
  const size_t OFF_W1   = 8388608;
  const size_t OFF_W2   = 16777216;
  const size_t OFF_W3   = 25165824;
  const size_t OFF_H1   = 33554432;
  const size_t OFF_QKV  = 41943040;
  const size_t OFF_QR   = 67108864;
  const size_t OFF_KR   = 75497472;
  const size_t OFF_VT   = 83886080;
  const size_t OFF_ATT  = 92274688;
  const size_t OFF_X2   = 100663296;
  const size_t OFF_H2   = 117440512;
  const size_t OFF_A1   = 33554432;   // reuse h1+qkv (dead by FFN)
  const size_t OFF_A3   = 67108864;   // reuse q/k/vt/att (dead by FFN)
  const size_t OFF_PART = 125829120;  // 4 x 16MB fp32 split-K partials (w2)
  const size_t NEEDED   = 125829120;
  const size_t NEED_SPLIT = OFF_PART + 67108864;
  if (ws_size < NEEDED) return;
  const bool use_split = (ws_size >= NEED_SPLIT);

  char* ws = (char*)d_ws;
  bf16_t* wqkv_bf = (bf16_t*)(ws + OFF_WQKV);
  bf16_t* wout_bf = (bf16_t*)(ws + OFF_WOUT);
  bf16_t* w1_bf   = (bf16_t*)(ws + OFF_W1);
  bf16_t* w2_bf   = (bf16_t*)(ws + OFF_W2);
  bf16_t* w3_bf   = (bf16_t*)(ws + OFF_W3);
  bf16_t* h1      = (bf16_t*)(ws + OFF_H1);
  bf16_t* qkv     = (bf16_t*)(ws + OFF_QKV);
  bf16_t* q_r     = (bf16_t*)(ws + OFF_QR);
  bf16_t* k_r     = (bf16_t*)(ws + OFF_KR);
  bf16_t* v_t     = (bf16_t*)(ws + OFF_VT);
  bf16_t* att     = (bf16_t*)(ws + OFF_ATT);
  float*  x2      = (float*)(ws + OFF_X2);
  bf16_t* h2      = (bf16_t*)(ws + OFF_H2);
  bf16_t* a1      = (bf16_t*)(ws + OFF_A1);
  bf16_t* a3      = (bf16_t*)(ws + OFF_A3);
  float*  part    = (float*)(ws + OFF_PART);
  float*  out     = (float*)d_out;

  f2bf_all_kernel<<<2048, 256, 0, stream>>>(w_qkv, w_out, w1, w2, w3,
                                            wqkv_bf, wout_bf, w1_bf, w2_bf, w3_bf);
  ln_kernel<<<NTOK, 256, 0, stream>>>(x, ln1_g, ln1_b, h1);
  gemm256<1><<<dim3(192, 1, 1), 512, 0, stream>>>(h1, wqkv_bf, b_qkv, nullptr, qkv,
                                                  NTOK, 3072, DIM, DIM);
  qknorm_rope_kernel<<<NTOK, 256, 0, stream>>>(qkv, qn_g, qn_b, kn_g, kn_b,
                                               rope_cos, rope_sin, q_r, k_r);
  vtrans_kernel<<<dim3(SEQ / 64, NB * HEADS), 256, 0, stream>>>(qkv, v_t);
  attn_kernel<<<256, 512, 0, stream>>>(q_r, k_r, v_t, att);
  gemm_bt<0><<<dim3(32 * 8, 1, 1), 256, 0, stream>>>(
      att, wout_bf, b_out, x, x2, NTOK, DIM, DIM, DIM);
  ln_kernel<<<NTOK, 256, 0, stream>>>(x2, ln2_g, ln2_b, h2);
  gemm256<1><<<dim3(256, 1, 1), 512, 0, stream>>>(h2, w1_bf, b1, nullptr, a1,
                                                  NTOK, FFND, DIM, DIM);
  gemm256<3><<<dim3(256, 1, 1), 512, 0, stream>>>(h2, w3_bf, b3, a1, a3,
                                                  NTOK, FFND, DIM, DIM);
  if (use_split) {
    gemm256<2><<<dim3(64, 1, 4), 512, 0, stream>>>(a3, w2_bf, nullptr, nullptr, part,
                                                   NTOK, DIM, FFND, FFND / 4);
    combine_kernel<<<2048, 256, 0, stream>>>(part, b2, x2, out, NTOK * DIM / 4);
  } else {
    gemm_bt<0><<<dim3(32 * 8, 1, 1), 256, 0, stream>>>(
        a3, w2_bf, b2, x2, out, NTOK, DIM, FFND, FFND);
  }
}

// Round 14
// 301.500 us; speedup vs baseline: 4.5307x; 1.1149x over previous
//
#include <hip/hip_runtime.h>
#include <hip/hip_bf16.h>

// ---------------------------------------------------------------------------
// Transformer layer: LN1 -> QKV GEMM -> QKnorm+RoPE -> flash attn -> outproj
//                    (+res) -> LN2 -> SwiGLU FFN (+res)
// B=2 S=2048 DIM=1024 H=16 HD=64 FFN=4096. fp32 I/O, bf16 MFMA compute.
// R14: restore R11 (empirical best, 299us). Three GEMM sync variants (R9
//      8-barrier counted / R11 1-barrier drain / R13 3-buf counted) all land
//      53-60us => fencing is not the binding constraint; R12 proved 256^2
//      tile cannot be >1 block/CU (128-reg accumulator). Locking best config.
// ---------------------------------------------------------------------------

typedef __bf16 bf16_t;
typedef bf16_t bf16x8 __attribute__((ext_vector_type(8)));
typedef bf16_t bf16x4 __attribute__((ext_vector_type(4)));
typedef float  f32x4  __attribute__((ext_vector_type(4)));
typedef float  f32x16 __attribute__((ext_vector_type(16)));

#define DIM   1024
#define HEADS 16
#define HD    64
#define FFND  4096
#define NB    2
#define SEQ   2048
#define NTOK  (NB * SEQ)   // 4096

#define GLOAD16(gp, lp) __builtin_amdgcn_global_load_lds( \
    (const __attribute__((address_space(1))) void*)(gp),  \
    (__attribute__((address_space(3))) void*)(lp), 16, 0, 0)

#define CVTPK(lo, hi_) ({ unsigned r_;                                        \
  asm("v_cvt_pk_bf16_f32 %0, %1, %2" : "=v"(r_) : "v"(lo), "v"(hi_)); r_; })
#define PLSWAP(a, b) asm("v_permlane32_swap_b32 %0, %1" : "+v"(a), "+v"(b))
#define SBAR() asm volatile("s_barrier" ::: "memory")

// ---------------- fp32 -> bf16 convert, all 5 weights in one launch --------
#define F2B_S0 786432
#define F2B_S1 262144
#define F2B_S2 1048576
#define F2B_S3 1048576
#define F2B_S4 1048576
#define F2B_C1 (F2B_S0)
#define F2B_C2 (F2B_C1 + F2B_S1)
#define F2B_C3 (F2B_C2 + F2B_S2)
#define F2B_C4 (F2B_C3 + F2B_S3)
#define F2B_N  (F2B_C4 + F2B_S4)

__global__ void f2bf_all_kernel(const float* __restrict__ s0, const float* __restrict__ s1,
                                const float* __restrict__ s2, const float* __restrict__ s3,
                                const float* __restrict__ s4,
                                bf16_t* __restrict__ d0, bf16_t* __restrict__ d1,
                                bf16_t* __restrict__ d2, bf16_t* __restrict__ d3,
                                bf16_t* __restrict__ d4) {
  int idx = blockIdx.x * blockDim.x + threadIdx.x;
  int stride = gridDim.x * blockDim.x;
  for (; idx < F2B_N; idx += stride) {
    const float* src; bf16_t* dst; int i;
    if (idx < F2B_C1)      { src = s0; dst = d0; i = idx; }
    else if (idx < F2B_C2) { src = s1; dst = d1; i = idx - F2B_C1; }
    else if (idx < F2B_C3) { src = s2; dst = d2; i = idx - F2B_C2; }
    else if (idx < F2B_C4) { src = s3; dst = d3; i = idx - F2B_C3; }
    else                   { src = s4; dst = d4; i = idx - F2B_C4; }
    float4 v = reinterpret_cast<const float4*>(src)[i];
    bf16x4 o;
    o[0] = (bf16_t)v.x; o[1] = (bf16_t)v.y; o[2] = (bf16_t)v.z; o[3] = (bf16_t)v.w;
    reinterpret_cast<bf16x4*>(dst)[i] = o;
  }
}

// ---------------- LayerNorm (one token per block, 256 thr) ----------------
__global__ __launch_bounds__(256) void ln_kernel(
    const float* __restrict__ x, const float* __restrict__ g,
    const float* __restrict__ b, bf16_t* __restrict__ out) {
  int t = blockIdx.x;
  int i = threadIdx.x;
  float4 v = reinterpret_cast<const float4*>(x + (size_t)t * DIM)[i];
  float s  = v.x + v.y + v.z + v.w;
  float s2 = v.x * v.x + v.y * v.y + v.z * v.z + v.w * v.w;
#pragma unroll
  for (int off = 32; off > 0; off >>= 1) {
    s  += __shfl_down(s, off, 64);
    s2 += __shfl_down(s2, off, 64);
  }
  __shared__ float red[2][4];
  int wid = i >> 6, lane = i & 63;
  if (lane == 0) { red[0][wid] = s; red[1][wid] = s2; }
  __syncthreads();
  float S  = red[0][0] + red[0][1] + red[0][2] + red[0][3];
  float S2 = red[1][0] + red[1][1] + red[1][2] + red[1][3];
  float mean = S * (1.0f / DIM);
  float var  = S2 * (1.0f / DIM) - mean * mean;
  float r = rsqrtf(var + 1e-6f);
  float vv[4] = {v.x, v.y, v.z, v.w};
  bf16x4 o;
#pragma unroll
  for (int j = 0; j < 4; ++j) {
    int d = i * 4 + j;
    o[j] = (bf16_t)((vv[j] - mean) * r * g[d] + b[d]);
  }
  *reinterpret_cast<bf16x4*>(out + (size_t)t * DIM + i * 4) = o;
}

// ---------------- gemm256: 256x256 tile, BK=64, 8 waves, de-phased --------
// OUT_MODE: 1 = bf16 + bias; 2 = fp32 partial (slice blockIdx.z, no bias);
//           3 = bf16 silu(comp)*(acc+bias)  [SwiGLU fused w3 epilogue]
// Per K-tile: vmcnt(0) [loads issued a full tile earlier -> latency-hidden]
// -> s_barrier [tile resident + prev reads consumed] -> issue 8 staging
// loads of t+1 -> 24 ds_reads + 64 MFMA, compiler-interleaved (fine lgkmcnt).
template <int OUT_MODE>
__global__ __launch_bounds__(512, 2) void gemm256(
    const bf16_t* __restrict__ A, const bf16_t* __restrict__ B,
    const float* __restrict__ bias, const bf16_t* __restrict__ comp,
    void* __restrict__ Cout, int M, int N, int Kfull, int Klen) {
  __shared__ __align__(16) bf16_t Al[2][256][64];
  __shared__ __align__(16) bf16_t Bl[2][256][64];
  const int nTn = N >> 8;
  const int nwg = gridDim.x;
  const int bid = blockIdx.x;
  const int swz = ((nwg & 7) == 0) ? ((bid & 7) * (nwg >> 3) + (bid >> 3)) : bid;
  const int bm = swz / nTn, bn = swz % nTn;
  const int k0base = blockIdx.z * Klen;
  const int NT = Klen >> 6;
  const int tid = threadIdx.x, wid = tid >> 6, lane = tid & 63;
  const int wm2 = wid >> 2, wn = wid & 3;        // 2 x 4 waves
  const int lr = lane & 15, lg = lane >> 4;
  const int strow = wid * 8 + (lane >> 3);
  const int stg   = ((lane & 7) ^ ((lane >> 3) & 7)) << 3;
  const bf16_t* Abase = A + (size_t)(bm * 256 + strow) * Kfull + k0base + stg;
  const bf16_t* Bbase = B + (size_t)(bn * 256 + strow) * Kfull + k0base + stg;

#define STAGE_A(buf, half, c, t)                                              \
  GLOAD16(Abase + (size_t)((half) * 128 + (c) * 64) * Kfull + (t) * 64,       \
          &Al[buf][(half) * 128 + (c) * 64 + wid * 8][0])
#define STAGE_B(buf, half, c, t)                                              \
  GLOAD16(Bbase + (size_t)((half) * 128 + (c) * 64) * Kfull + (t) * 64,       \
          &Bl[buf][(half) * 128 + (c) * 64 + wid * 8][0])

  f32x4 acc[8][4] = {};
  // prologue: stage tile 0 into buf 0
  STAGE_A(0, 0, 0, 0); STAGE_A(0, 0, 1, 0); STAGE_A(0, 1, 0, 0); STAGE_A(0, 1, 1, 0);
  STAGE_B(0, 0, 0, 0); STAGE_B(0, 0, 1, 0); STAGE_B(0, 1, 0, 0); STAGE_B(0, 1, 1, 0);

  for (int t = 0; t < NT; ++t) {
    const int cur = t & 1, nxt = cur ^ 1;
    asm volatile("s_waitcnt vmcnt(0)" ::: "memory");   // tile t landed (mine)
    SBAR();                                            // all waves: tile t visible;
                                                       // t-1 reads all consumed
    if (t + 1 < NT) {                                  // stage t+1; rides thru tile
      STAGE_A(nxt, 0, 0, t + 1); STAGE_A(nxt, 0, 1, t + 1);
      STAGE_A(nxt, 1, 0, t + 1); STAGE_A(nxt, 1, 1, t + 1);
      STAGE_B(nxt, 0, 0, t + 1); STAGE_B(nxt, 0, 1, t + 1);
      STAGE_B(nxt, 1, 0, t + 1); STAGE_B(nxt, 1, 1, t + 1);
    }
    // k-chunk 0/1: read frags + 32 MFMA each; no fences -> compiler
    // interleaves ds_read/MFMA with fine-grained lgkmcnt.
#pragma unroll
    for (int ks = 0; ks < 2; ++ks) {
      bf16x8 af[8], bfr[4];
#pragma unroll
      for (int nf = 0; nf < 4; ++nf) {
        const int row = wn * 64 + nf * 16 + lr;
        const int g = ((ks * 4 + lg) ^ (lane & 7)) << 3;
        bfr[nf] = *reinterpret_cast<const bf16x8*>(&Bl[cur][row][g]);
      }
#pragma unroll
      for (int mf = 0; mf < 8; ++mf) {
        const int row = wm2 * 128 + mf * 16 + lr;
        const int g = ((ks * 4 + lg) ^ (lane & 7)) << 3;
        af[mf] = *reinterpret_cast<const bf16x8*>(&Al[cur][row][g]);
      }
      __builtin_amdgcn_s_setprio(1);
#pragma unroll
      for (int mf = 0; mf < 8; ++mf)
#pragma unroll
        for (int nf = 0; nf < 4; ++nf)
          acc[mf][nf] = __builtin_amdgcn_mfma_f32_16x16x32_bf16(af[mf], bfr[nf], acc[mf][nf], 0, 0, 0);
      __builtin_amdgcn_s_setprio(0);
    }
  }
#undef STAGE_A
#undef STAGE_B
  const int r0 = lg * 4;
#pragma unroll
  for (int mf = 0; mf < 8; ++mf) {
#pragma unroll
    for (int r = 0; r < 4; ++r) {
      const int row = bm * 256 + wm2 * 128 + mf * 16 + r0 + r;
#pragma unroll
      for (int nf = 0; nf < 4; ++nf) {
        const int col = bn * 256 + wn * 64 + nf * 16 + lr;
        float v = acc[mf][nf][r];
        if (OUT_MODE == 1) {
          v += bias[col];
          reinterpret_cast<bf16_t*>(Cout)[(size_t)row * N + col] = (bf16_t)v;
        } else if (OUT_MODE == 2) {
          float* P = reinterpret_cast<float*>(Cout) + (size_t)blockIdx.z * M * N;
          P[(size_t)row * N + col] = v;
        } else {
          v += bias[col];
          float c1 = (float)comp[(size_t)row * N + col];
          float sg = c1 / (1.0f + __expf(-c1));
          reinterpret_cast<bf16_t*>(Cout)[(size_t)row * N + col] = (bf16_t)(sg * v);
        }
      }
    }
  }
}

// ---------------- combine split-K partials + bias + residual ---------------
__global__ void combine_kernel(const float* __restrict__ part,
                               const float* __restrict__ bias,
                               const float* __restrict__ res,
                               float* __restrict__ out, int n4) {
  const int slice = NTOK * DIM / 4;
  int i = blockIdx.x * blockDim.x + threadIdx.x;
  int stride = gridDim.x * blockDim.x;
  const float4* p = reinterpret_cast<const float4*>(part);
  const float4* r4 = reinterpret_cast<const float4*>(res);
  const float4* b4 = reinterpret_cast<const float4*>(bias);
  float4* o4 = reinterpret_cast<float4*>(out);
  for (; i < n4; i += stride) {
    float4 a = p[i], b = p[i + slice], c = p[i + 2 * slice], d = p[i + 3 * slice];
    float4 rr = r4[i];
    float4 bb = b4[i & 255];
    float4 o;
    o.x = a.x + b.x + c.x + d.x + bb.x + rr.x;
    o.y = a.y + b.y + c.y + d.y + bb.y + rr.y;
    o.z = a.z + b.z + c.z + d.z + bb.z + rr.z;
    o.w = a.w + b.w + c.w + d.w + bb.w + rr.w;
    o4[i] = o;
  }
}

// ---------------- GEMM 128x128 (m97-style), out-proj / fallback ------------
// OUT_MODE: 0 = fp32 + bias + res; 2 = fp32 partial (slice z)
template <int OUT_MODE>
__global__ __launch_bounds__(256) void gemm_bt(
    const bf16_t* __restrict__ A, const bf16_t* __restrict__ B,
    const float* __restrict__ bias, const float* __restrict__ res,
    void* __restrict__ Cout, int M, int N, int Kfull, int Klen) {
  __shared__ bf16_t As[128][32];
  __shared__ bf16_t Bs[128][32];
  const int nTn = N >> 7;
  const int nwg = gridDim.x;
  const int bid = blockIdx.x;
  const int swz = ((nwg & 7) == 0) ? ((bid & 7) * (nwg >> 3) + (bid >> 3)) : bid;
  const int bm = swz / nTn;
  const int bn = swz % nTn;
  const int k0base = blockIdx.z * Klen;
  const int tid  = threadIdx.x;
  const int wid  = tid >> 6;
  const int lane = tid & 63;
  const int wm = (wid >> 1) * 64, wn = (wid & 1) * 64;
  const int lr = lane & 15;
  const int gq = lane >> 4;
  const int sr = lane >> 2;
  const int sg = lane & 3;
  const int cS = ((sg ^ ((sr >> 1) & 3)) << 3);
  const int swg = ((gq ^ ((lr >> 1) & 3)) << 3);
  f32x4 acc[4][4] = {};
  const bf16_t* Ag0 = A + (size_t)(bm * 128 + wid * 16 + sr) * Kfull + k0base + cS;
  const bf16_t* Ag1 = Ag0 + (size_t)64 * Kfull;
  const bf16_t* Bg0 = B + (size_t)(bn * 128 + wid * 16 + sr) * Kfull + k0base + cS;
  const bf16_t* Bg1 = Bg0 + (size_t)64 * Kfull;
  bf16_t* ldsA0 = &As[wid * 16][0];
  bf16_t* ldsA1 = &As[64 + wid * 16][0];
  bf16_t* ldsB0 = &Bs[wid * 16][0];
  bf16_t* ldsB1 = &Bs[64 + wid * 16][0];
  for (int k0 = 0; k0 < Klen; k0 += 32) {
    __syncthreads();
    GLOAD16(Ag0 + k0, ldsA0);
    GLOAD16(Ag1 + k0, ldsA1);
    GLOAD16(Bg0 + k0, ldsB0);
    GLOAD16(Bg1 + k0, ldsB1);
    __syncthreads();
    bf16x8 af[4], bfr[4];
#pragma unroll
    for (int mi = 0; mi < 4; ++mi)
      af[mi] = *reinterpret_cast<const bf16x8*>(&As[wm + mi * 16 + lr][swg]);
#pragma unroll
    for (int ni = 0; ni < 4; ++ni)
      bfr[ni] = *reinterpret_cast<const bf16x8*>(&Bs[wn + ni * 16 + lr][swg]);
#pragma unroll
    for (int mi = 0; mi < 4; ++mi)
#pragma unroll
      for (int ni = 0; ni < 4; ++ni)
        acc[mi][ni] = __builtin_amdgcn_mfma_f32_16x16x32_bf16(af[mi], bfr[ni], acc[mi][ni], 0, 0, 0);
  }
  const int r0 = (lane >> 4) * 4;
#pragma unroll
  for (int mi = 0; mi < 4; ++mi) {
#pragma unroll
    for (int r = 0; r < 4; ++r) {
      int row = bm * 128 + wm + mi * 16 + r0 + r;
#pragma unroll
      for (int ni = 0; ni < 4; ++ni) {
        int col = bn * 128 + wn + ni * 16 + lr;
        float v = acc[mi][ni][r];
        if (OUT_MODE == 0) {
          v += bias[col] + res[(size_t)row * N + col];
          reinterpret_cast<float*>(Cout)[(size_t)row * N + col] = v;
        } else {
          float* P = reinterpret_cast<float*>(Cout) + (size_t)blockIdx.z * M * N;
          P[(size_t)row * N + col] = v;
        }
      }
    }
  }
}

// ---------------- QK-norm (full-dim LN) + RoPE + BHSD repack ---------------
// Q is pre-scaled by log2(e)/8 so attention computes p = 2^(s_raw) directly.
__global__ __launch_bounds__(256) void qknorm_rope_kernel(
    const bf16_t* __restrict__ qkv,
    const float* __restrict__ qg, const float* __restrict__ qb,
    const float* __restrict__ kg, const float* __restrict__ kb,
    const float* __restrict__ rc, const float* __restrict__ rs,
    bf16_t* __restrict__ q_r, bf16_t* __restrict__ k_r) {
  int t = blockIdx.x;
  int b = t >> 11, s = t & 2047;
  const bf16_t* p = qkv + (size_t)t * 3072;
  int i = threadIdx.x;
  bf16x4 qv = *reinterpret_cast<const bf16x4*>(p + i * 4);
  bf16x4 kv = *reinterpret_cast<const bf16x4*>(p + 1024 + i * 4);
  float q4[4], k4[4];
  float sq = 0.f, sq2 = 0.f, sk = 0.f, sk2 = 0.f;
#pragma unroll
  for (int j = 0; j < 4; ++j) {
    q4[j] = (float)qv[j]; k4[j] = (float)kv[j];
    sq += q4[j]; sq2 += q4[j] * q4[j];
    sk += k4[j]; sk2 += k4[j] * k4[j];
  }
#pragma unroll
  for (int off = 32; off > 0; off >>= 1) {
    sq  += __shfl_down(sq, off, 64);
    sq2 += __shfl_down(sq2, off, 64);
    sk  += __shfl_down(sk, off, 64);
    sk2 += __shfl_down(sk2, off, 64);
  }
  __shared__ float red[4][4];
  int wid = i >> 6, lane = i & 63;
  if (lane == 0) { red[0][wid] = sq; red[1][wid] = sq2; red[2][wid] = sk; red[3][wid] = sk2; }
  __syncthreads();
  float Sq  = red[0][0] + red[0][1] + red[0][2] + red[0][3];
  float Sq2 = red[1][0] + red[1][1] + red[1][2] + red[1][3];
  float Sk  = red[2][0] + red[2][1] + red[2][2] + red[2][3];
  float Sk2 = red[3][0] + red[3][1] + red[3][2] + red[3][3];
  float mq = Sq * (1.0f / DIM);
  float vq = Sq2 * (1.0f / DIM) - mq * mq;
  float rq = rsqrtf(vq + 1e-6f);
  float mk = Sk * (1.0f / DIM);
  float vk = Sk2 * (1.0f / DIM) - mk * mk;
  float rk = rsqrtf(vk + 1e-6f);
  const float QS = 0.18033688011f;   // log2(e)/8 folded into Q
#pragma unroll
  for (int j = 0; j < 4; ++j) {
    int d = i * 4 + j, h = d >> 6, hd = d & 63, dp = d ^ 32;
    float c  = rc[s * HD + hd];
    float sn = rs[s * HD + hd];
    float qn  = (q4[j] - mq) * rq * qg[d] + qb[d];
    float qpn = ((float)p[dp] - mq) * rq * qg[dp] + qb[dp];
    float qo  = qn * c + ((hd < 32) ? -qpn : qpn) * sn;
    float kn  = (k4[j] - mk) * rk * kg[d] + kb[d];
    float kpn = ((float)p[1024 + dp] - mk) * rk * kg[dp] + kb[dp];
    float ko  = kn * c + ((hd < 32) ? -kpn : kpn) * sn;
    size_t oi = ((size_t)(b * HEADS + h) * SEQ + s) * HD + hd;
    q_r[oi] = (bf16_t)(qo * QS);
    k_r[oi] = (bf16_t)ko;
  }
}

// ---------------- V transpose: qkv[b,s,2048+h*64+d] -> v_t[bh][d][s] -------
__global__ __launch_bounds__(256) void vtrans_kernel(
    const bf16_t* __restrict__ qkv, bf16_t* __restrict__ v_t) {
  __shared__ bf16_t T[64][72];
  const int st = blockIdx.x;
  const int bh = blockIdx.y;
  const int b = bh >> 4, h = bh & 15;
  const int tid = threadIdx.x;
  const int r = tid >> 2, c = (tid & 3) * 8;
  const bf16_t* src = qkv + (size_t)(b * SEQ + st * 64 + r) * 3072 + 2048 + h * 64;
  *reinterpret_cast<bf16x8*>(&T[r][c])      = *reinterpret_cast<const bf16x8*>(src + c);
  *reinterpret_cast<bf16x8*>(&T[r][c + 32]) = *reinterpret_cast<const bf16x8*>(src + c + 32);
  __syncthreads();
  bf16x8 o0, o1;
#pragma unroll
  for (int j = 0; j < 8; ++j) { o0[j] = T[c + j][r]; o1[j] = T[c + 32 + j][r]; }
  bf16_t* dst = v_t + ((size_t)bh * 64 + r) * SEQ + st * 64;
  *reinterpret_cast<bf16x8*>(dst + c)      = o0;
  *reinterpret_cast<bf16x8*>(dst + c + 32) = o1;
}

// ---------------- Flash attention: granule-major LDS + in-block K-split ----
__global__ __launch_bounds__(512, 2) void attn_kernel(
    const bf16_t* __restrict__ q_r, const bf16_t* __restrict__ k_r,
    const bf16_t* __restrict__ v_t, bf16_t* __restrict__ attn_out) {
  __shared__ __align__(16) char smem[69632];
  bf16_t* KsB = (bf16_t*)smem;
  bf16_t* VsB = (bf16_t*)(smem + 32768);
  float*  Xch = (float*)smem;
  const int bid = blockIdx.x;
  const int hh = bid & 31;
  const int qt = bid >> 5;
  const int bidx = hh >> 4, h = hh & 15;
  const int tid = threadIdx.x, wid = tid >> 6, lane = tid & 63;
  const int kh = wid >> 2, ww = wid & 3;
  const int lq = lane & 31, hi = lane >> 5;
  const int qA = qt * 256 + ww * 64 + lq;
  const int qB = qA + 32;
  const bf16_t* Qp = q_r + (size_t)hh * SEQ * HD;
  const bf16_t* Kp = k_r + (size_t)hh * SEQ * HD + (size_t)kh * 1024 * HD;
  const bf16_t* Vp = v_t + (size_t)hh * HD * SEQ + kh * 1024;
  bf16_t* Ks0 = KsB + kh * 2 * 4096;
  bf16_t* Vs0 = VsB + kh * 2 * 4096;
  bf16x8 qfA[4], qfB[4];
#pragma unroll
  for (int kdt = 0; kdt < 4; ++kdt) {
    qfA[kdt] = *reinterpret_cast<const bf16x8*>(Qp + (size_t)qA * HD + kdt * 16 + hi * 8);
    qfB[kdt] = *reinterpret_cast<const bf16x8*>(Qp + (size_t)qB * HD + kdt * 16 + hi * 8);
  }
  f32x16 oA0 = {}, oA1 = {}, oB0 = {}, oB1 = {};
  float lA = 0.f, lB = 0.f;
  const int kSrcA = lane * HD + ww * 8;
  const int kSrcB = lane * HD + (ww + 4) * 8;
  const int vSrcA = lane * SEQ + ww * 8;
  const int vSrcB = lane * SEQ + (ww + 4) * 8;
  const int ldsA = ww * 512;
  const int ldsB = 2048 + ww * 512;
  GLOAD16(Kp + kSrcA, &Ks0[ldsA]);
  GLOAD16(Kp + kSrcB, &Ks0[ldsB]);
  GLOAD16(Vp + vSrcA, &Vs0[ldsA]);
  GLOAD16(Vp + vSrcB, &Vs0[ldsB]);
  __syncthreads();
  const int NT = 1024 / 64;
  for (int kt = 0; kt < NT; ++kt) {
    const int cur = kt & 1, nxt = cur ^ 1;
    if (kt + 1 < NT) {
      GLOAD16(Kp + (kt + 1) * (64 * HD) + kSrcA, &Ks0[nxt * 4096 + ldsA]);
      GLOAD16(Kp + (kt + 1) * (64 * HD) + kSrcB, &Ks0[nxt * 4096 + ldsB]);
      GLOAD16(Vp + (kt + 1) * 64 + vSrcA, &Vs0[nxt * 4096 + ldsA]);
      GLOAD16(Vp + (kt + 1) * 64 + vSrcB, &Vs0[nxt * 4096 + ldsB]);
    }
    f32x16 sA0 = {}, sA1 = {}, sB0 = {}, sB1 = {};
#pragma unroll
    for (int kdt = 0; kdt < 4; ++kdt) {
      const int goff = cur * 4096 + (kdt * 2 + hi) * 512;
      bf16x8 kf0 = *reinterpret_cast<const bf16x8*>(&Ks0[goff + lq * 8]);
      bf16x8 kf1 = *reinterpret_cast<const bf16x8*>(&Ks0[goff + (lq + 32) * 8]);
      sA0 = __builtin_amdgcn_mfma_f32_32x32x16_bf16(kf0, qfA[kdt], sA0, 0, 0, 0);
      sA1 = __builtin_amdgcn_mfma_f32_32x32x16_bf16(kf1, qfA[kdt], sA1, 0, 0, 0);
      sB0 = __builtin_amdgcn_mfma_f32_32x32x16_bf16(kf0, qfB[kdt], sB0, 0, 0, 0);
      sB1 = __builtin_amdgcn_mfma_f32_32x32x16_bf16(kf1, qfB[kdt], sB1, 0, 0, 0);
    }
#pragma unroll
    for (int i = 0; i < 16; ++i) sA0[i] = __builtin_amdgcn_exp2f(sA0[i]);
#pragma unroll
    for (int i = 0; i < 16; ++i) sA1[i] = __builtin_amdgcn_exp2f(sA1[i]);
#pragma unroll
    for (int i = 0; i < 16; ++i) sB0[i] = __builtin_amdgcn_exp2f(sB0[i]);
#pragma unroll
    for (int i = 0; i < 16; ++i) sB1[i] = __builtin_amdgcn_exp2f(sB1[i]);
    {
      f32x16 t = sA0 + sA1;
      float a = ((t[0] + t[8]) + (t[4] + t[12])) + ((t[2] + t[10]) + (t[6] + t[14]));
      float b = ((t[1] + t[9]) + (t[5] + t[13])) + ((t[3] + t[11]) + (t[7] + t[15]));
      lA += a + b;
      f32x16 u = sB0 + sB1;
      float c = ((u[0] + u[8]) + (u[4] + u[12])) + ((u[2] + u[10]) + (u[6] + u[14]));
      float d = ((u[1] + u[9]) + (u[5] + u[13])) + ((u[3] + u[11]) + (u[7] + u[15]));
      lB += c + d;
    }
#pragma unroll
    for (int tt = 0; tt < 2; ++tt) {
#pragma unroll
      for (int ks = 0; ks < 2; ++ks) {
        const f32x16& pA = tt ? sA1 : sA0;
        const f32x16& pB = tt ? sB1 : sB0;
        unsigned a0, b0, c0, d0, a1, b1, c1, d1;
        if (ks == 0) {
          a0 = CVTPK(pA[0], pA[1]); b0 = CVTPK(pA[4], pA[5]);
          c0 = CVTPK(pA[2], pA[3]); d0 = CVTPK(pA[6], pA[7]);
          a1 = CVTPK(pB[0], pB[1]); b1 = CVTPK(pB[4], pB[5]);
          c1 = CVTPK(pB[2], pB[3]); d1 = CVTPK(pB[6], pB[7]);
        } else {
          a0 = CVTPK(pA[8], pA[9]);   b0 = CVTPK(pA[12], pA[13]);
          c0 = CVTPK(pA[10], pA[11]); d0 = CVTPK(pA[14], pA[15]);
          a1 = CVTPK(pB[8], pB[9]);   b1 = CVTPK(pB[12], pB[13]);
          c1 = CVTPK(pB[10], pB[11]); d1 = CVTPK(pB[14], pB[15]);
        }
        PLSWAP(a0, b0); PLSWAP(c0, d0); PLSWAP(a1, b1); PLSWAP(c1, d1);
        union { unsigned u[4]; bf16x8 v; } pfA, pfB;
        pfA.u[0] = a0; pfA.u[1] = c0; pfA.u[2] = b0; pfA.u[3] = d0;
        pfB.u[0] = a1; pfB.u[1] = c1; pfB.u[2] = b1; pfB.u[3] = d1;
        const int gv = cur * 4096 + (tt * 4 + ks * 2 + hi) * 512;
        bf16x8 vf0 = *reinterpret_cast<const bf16x8*>(&Vs0[gv + lq * 8]);
        bf16x8 vf1 = *reinterpret_cast<const bf16x8*>(&Vs0[gv + (lq + 32) * 8]);
        oA0 = __builtin_amdgcn_mfma_f32_32x32x16_bf16(vf0, pfA.v, oA0, 0, 0, 0);
        oA1 = __builtin_amdgcn_mfma_f32_32x32x16_bf16(vf1, pfA.v, oA1, 0, 0, 0);
        oB0 = __builtin_amdgcn_mfma_f32_32x32x16_bf16(vf0, pfB.v, oB0, 0, 0, 0);
        oB1 = __builtin_amdgcn_mfma_f32_32x32x16_bf16(vf1, pfB.v, oB1, 0, 0, 0);
      }
    }
    __syncthreads();
  }
  lA += __shfl_xor(lA, 32, 64);
  lB += __shfl_xor(lB, 32, 64);
  if (kh == 1) {
    float* my = Xch + (size_t)(ww * 64 + lane) * 68;
#pragma unroll
    for (int g = 0; g < 4; ++g) {
      *reinterpret_cast<float4*>(my + g * 4)      = make_float4(oA0[g*4], oA0[g*4+1], oA0[g*4+2], oA0[g*4+3]);
      *reinterpret_cast<float4*>(my + 16 + g * 4) = make_float4(oA1[g*4], oA1[g*4+1], oA1[g*4+2], oA1[g*4+3]);
      *reinterpret_cast<float4*>(my + 32 + g * 4) = make_float4(oB0[g*4], oB0[g*4+1], oB0[g*4+2], oB0[g*4+3]);
      *reinterpret_cast<float4*>(my + 48 + g * 4) = make_float4(oB1[g*4], oB1[g*4+1], oB1[g*4+2], oB1[g*4+3]);
    }
    my[64] = lA; my[65] = lB;
  }
  __syncthreads();
  if (kh == 0) {
    const float* pr = Xch + (size_t)(ww * 64 + lane) * 68;
#pragma unroll
    for (int i = 0; i < 16; ++i) {
      oA0[i] += pr[i];      oA1[i] += pr[16 + i];
      oB0[i] += pr[32 + i]; oB1[i] += pr[48 + i];
    }
    float invA = 1.0f / (lA + pr[64]);
    float invB = 1.0f / (lB + pr[65]);
    bf16_t* orowA = attn_out + ((size_t)(bidx * SEQ + qA)) * DIM + h * 64;
    bf16_t* orowB = attn_out + ((size_t)(bidx * SEQ + qB)) * DIM + h * 64;
#pragma unroll
    for (int g = 0; g < 4; ++g) {
      bf16x4 wA0, wA1, wB0, wB1;
#pragma unroll
      for (int j = 0; j < 4; ++j) {
        wA0[j] = (bf16_t)(oA0[g * 4 + j] * invA);
        wA1[j] = (bf16_t)(oA1[g * 4 + j] * invA);
        wB0[j] = (bf16_t)(oB0[g * 4 + j] * invB);
        wB1[j] = (bf16_t)(oB1[g * 4 + j] * invB);
      }
      *reinterpret_cast<bf16x4*>(orowA + g * 8 + 4 * hi)      = wA0;
      *reinterpret_cast<bf16x4*>(orowA + 32 + g * 8 + 4 * hi) = wA1;
      *reinterpret_cast<bf16x4*>(orowB + g * 8 + 4 * hi)      = wB0;
      *reinterpret_cast<bf16x4*>(orowB + 32 + g * 8 + 4 * hi) = wB1;
    }
  }
}

// ---------------------------------------------------------------------------
extern "C" void kernel_launch(void* const* d_in, const int* in_sizes, int n_in,
                              void* d_out, int out_size, void* d_ws, size_t ws_size,
                              hipStream_t stream) {
  const float* x        = (const float*)d_in[0];
  const float* rope_cos = (const float*)d_in[1];
  const float* rope_sin = (const float*)d_in[2];
  const float* w_qkv    = (const float*)d_in[3];
  const float* b_qkv    = (const float*)d_in[4];
  const float* w_out    = (const float*)d_in[5];
  const float* b_out    = (const float*)d_in[6];
  const float* qn_g     = (const float*)d_in[7];
  const float* qn_b     = (const float*)d_in[8];
  const float* kn_g     = (const float*)d_in[9];
  const float* kn_b     = (const float*)d_in[10];
  const float* ln1_g    = (const float*)d_in[11];
  const float* ln1_b    = (const float*)d_in[12];
  const float* ln2_g    = (const float*)d_in[13];
  const float* ln2_b    = (const float*)d_in[14];
  const float* w1       = (const float*)d_in[15];
  const float* b1       = (const float*)d_in[16];
  const float* w2       = (const float*)d_in[17];
  const float* b2       = (const float*)d_in[18];
  const float* w3       = (const float*)d_in[19];
  const float* b3       = (const float*)d_in[20];

  const size_t OFF_WQKV = 0;
  const size_t OFF_WOUT = 6291456;
  const size_t OFF_W1   = 8388608;
  const size_t OFF_W2   = 16777216;
  const size_t OFF_W3   = 25165824;
  const size_t OFF_H1   = 33554432;
  const size_t OFF_QKV  = 41943040;
  const size_t OFF_QR   = 67108864;
  const size_t OFF_KR   = 75497472;
  const size_t OFF_VT   = 83886080;
  const size_t OFF_ATT  = 92274688;
  const size_t OFF_X2   = 100663296;
  const size_t OFF_H2   = 117440512;
  const size_t OFF_PART = 125829120;  // 4 x 16MB fp32 split-K partials (w2)
  const size_t NEEDED   = 125829120;
  const size_t NEED_SPLIT = OFF_PART + 67108864;
  if (ws_size < NEEDED) return;
  const bool use_split = (ws_size >= NEED_SPLIT);

  char* ws = (char*)d_ws;
  bf16_t* wqkv_bf = (bf16_t*)(ws + OFF_WQKV);
  bf16_t* wout_bf = (bf16_t*)(ws + OFF_WOUT);
  bf16_t* w1_bf   = (bf16_t*)(ws + OFF_W1);
  bf16_t* w2_bf   = (bf16_t*)(ws + OFF_W2);
  bf16_t* w3_bf   = (bf16_t*)(ws + OFF_W3);
  bf16_t* h1      = (bf16_t*)(ws + OFF_H1);
  bf16_t* qkv     = (bf16_t*)(ws + OFF_QKV);
  bf16_t* q_r     = (bf16_t*)(ws + OFF_QR);
  bf16_t* k_r     = (bf16_t*)(ws + OFF_KR);
  bf16_t* v_t     = (bf16_t*)(ws + OFF_VT);
  bf16_t* att     = (bf16_t*)(ws + OFF_ATT);
  float*  x2      = (float*)(ws + OFF_X2);
  bf16_t* h2      = (bf16_t*)(ws + OFF_H2);
  bf16_t* a1      = (bf16_t*)(ws + OFF_H1);   // reuse h1+qkv (dead by FFN)
  bf16_t* a3      = (bf16_t*)(ws + OFF_QR);   // reuse q/k/vt/att (dead by FFN)
  float*  part    = (float*)(ws + OFF_PART);
  float*  out     = (float*)d_out;

  f2bf_all_kernel<<<2048, 256, 0, stream>>>(w_qkv, w_out, w1, w2, w3,
                                            wqkv_bf, wout_bf, w1_bf, w2_bf, w3_bf);
  ln_kernel<<<NTOK, 256, 0, stream>>>(x, ln1_g, ln1_b, h1);
  gemm256<1><<<dim3(192, 1, 1), 512, 0, stream>>>(h1, wqkv_bf, b_qkv, nullptr, qkv,
                                                  NTOK, 3072, DIM, DIM);
  qknorm_rope_kernel<<<NTOK, 256, 0, stream>>>(qkv, qn_g, qn_b, kn_g, kn_b,
                                               rope_cos, rope_sin, q_r, k_r);
  vtrans_kernel<<<dim3(SEQ / 64, NB * HEADS), 256, 0, stream>>>(qkv, v_t);
  attn_kernel<<<256, 512, 0, stream>>>(q_r, k_r, v_t, att);
  gemm_bt<0><<<dim3(32 * 8, 1, 1), 256, 0, stream>>>(
      att, wout_bf, b_out, x, x2, NTOK, DIM, DIM, DIM);
  ln_kernel<<<NTOK, 256, 0, stream>>>(x2, ln2_g, ln2_b, h2);
  gemm256<1><<<dim3(256, 1, 1), 512, 0, stream>>>(h2, w1_bf, b1, nullptr, a1,
                                                  NTOK, FFND, DIM, DIM);
  gemm256<3><<<dim3(256, 1, 1), 512, 0, stream>>>(h2, w3_bf, b3, a1, a3,
                                                  NTOK, FFND, DIM, DIM);
  if (use_split) {
    gemm256<2><<<dim3(64, 1, 4), 512, 0, stream>>>(a3, w2_bf, nullptr, nullptr, part,
                                                   NTOK, DIM, FFND, FFND / 4);
    combine_kernel<<<2048, 256, 0, stream>>>(part, b2, x2, out, NTOK * DIM / 4);
  } else {
    gemm_bt<0><<<dim3(32 * 8, 1, 1), 256, 0, stream>>>(
        a3, w2_bf, b2, x2, out, NTOK, DIM, FFND, FFND);
  }
}

// Round 15
// 285.767 us; speedup vs baseline: 4.7802x; 1.0551x over previous
//
#include <hip/hip_runtime.h>
#include <hip/hip_bf16.h>

// ---------------------------------------------------------------------------
// Transformer layer: LN1 -> QKV GEMM -> QKnorm+RoPE -> flash attn -> outproj
//                    (+res) -> LN2 -> SwiGLU FFN (+res)
// B=2 S=2048 DIM=1024 H=16 HD=64 FFN=4096. fp32 I/O, bf16 MFMA compute.
// R15: R14 config (verified best ~300us) + qknorm RoPE-pair via shfl_xor
//      (pair element d^32 lives in lane^8 -- reuse its normalized value
//      instead of scalar reload + renormalize). GEMM/attention unchanged:
//      gemm256 rate-plateau fully characterized over 4 sync structures.
// ---------------------------------------------------------------------------

typedef __bf16 bf16_t;
typedef bf16_t bf16x8 __attribute__((ext_vector_type(8)));
typedef bf16_t bf16x4 __attribute__((ext_vector_type(4)));
typedef float  f32x4  __attribute__((ext_vector_type(4)));
typedef float  f32x16 __attribute__((ext_vector_type(16)));

#define DIM   1024
#define HEADS 16
#define HD    64
#define FFND  4096
#define NB    2
#define SEQ   2048
#define NTOK  (NB * SEQ)   // 4096

#define GLOAD16(gp, lp) __builtin_amdgcn_global_load_lds( \
    (const __attribute__((address_space(1))) void*)(gp),  \
    (__attribute__((address_space(3))) void*)(lp), 16, 0, 0)

#define CVTPK(lo, hi_) ({ unsigned r_;                                        \
  asm("v_cvt_pk_bf16_f32 %0, %1, %2" : "=v"(r_) : "v"(lo), "v"(hi_)); r_; })
#define PLSWAP(a, b) asm("v_permlane32_swap_b32 %0, %1" : "+v"(a), "+v"(b))
#define SBAR() asm volatile("s_barrier" ::: "memory")

// ---------------- fp32 -> bf16 convert, all 5 weights in one launch --------
#define F2B_S0 786432
#define F2B_S1 262144
#define F2B_S2 1048576
#define F2B_S3 1048576
#define F2B_S4 1048576
#define F2B_C1 (F2B_S0)
#define F2B_C2 (F2B_C1 + F2B_S1)
#define F2B_C3 (F2B_C2 + F2B_S2)
#define F2B_C4 (F2B_C3 + F2B_S3)
#define F2B_N  (F2B_C4 + F2B_S4)

__global__ void f2bf_all_kernel(const float* __restrict__ s0, const float* __restrict__ s1,
                                const float* __restrict__ s2, const float* __restrict__ s3,
                                const float* __restrict__ s4,
                                bf16_t* __restrict__ d0, bf16_t* __restrict__ d1,
                                bf16_t* __restrict__ d2, bf16_t* __restrict__ d3,
                                bf16_t* __restrict__ d4) {
  int idx = blockIdx.x * blockDim.x + threadIdx.x;
  int stride = gridDim.x * blockDim.x;
  for (; idx < F2B_N; idx += stride) {
    const float* src; bf16_t* dst; int i;
    if (idx < F2B_C1)      { src = s0; dst = d0; i = idx; }
    else if (idx < F2B_C2) { src = s1; dst = d1; i = idx - F2B_C1; }
    else if (idx < F2B_C3) { src = s2; dst = d2; i = idx - F2B_C2; }
    else if (idx < F2B_C4) { src = s3; dst = d3; i = idx - F2B_C3; }
    else                   { src = s4; dst = d4; i = idx - F2B_C4; }
    float4 v = reinterpret_cast<const float4*>(src)[i];
    bf16x4 o;
    o[0] = (bf16_t)v.x; o[1] = (bf16_t)v.y; o[2] = (bf16_t)v.z; o[3] = (bf16_t)v.w;
    reinterpret_cast<bf16x4*>(dst)[i] = o;
  }
}

// ---------------- LayerNorm (one token per block, 256 thr) ----------------
__global__ __launch_bounds__(256) void ln_kernel(
    const float* __restrict__ x, const float* __restrict__ g,
    const float* __restrict__ b, bf16_t* __restrict__ out) {
  int t = blockIdx.x;
  int i = threadIdx.x;
  float4 v = reinterpret_cast<const float4*>(x + (size_t)t * DIM)[i];
  float s  = v.x + v.y + v.z + v.w;
  float s2 = v.x * v.x + v.y * v.y + v.z * v.z + v.w * v.w;
#pragma unroll
  for (int off = 32; off > 0; off >>= 1) {
    s  += __shfl_down(s, off, 64);
    s2 += __shfl_down(s2, off, 64);
  }
  __shared__ float red[2][4];
  int wid = i >> 6, lane = i & 63;
  if (lane == 0) { red[0][wid] = s; red[1][wid] = s2; }
  __syncthreads();
  float S  = red[0][0] + red[0][1] + red[0][2] + red[0][3];
  float S2 = red[1][0] + red[1][1] + red[1][2] + red[1][3];
  float mean = S * (1.0f / DIM);
  float var  = S2 * (1.0f / DIM) - mean * mean;
  float r = rsqrtf(var + 1e-6f);
  float vv[4] = {v.x, v.y, v.z, v.w};
  bf16x4 o;
#pragma unroll
  for (int j = 0; j < 4; ++j) {
    int d = i * 4 + j;
    o[j] = (bf16_t)((vv[j] - mean) * r * g[d] + b[d]);
  }
  *reinterpret_cast<bf16x4*>(out + (size_t)t * DIM + i * 4) = o;
}

// ---------------- gemm256: 256x256 tile, BK=64, 8 waves, de-phased --------
// OUT_MODE: 1 = bf16 + bias; 2 = fp32 partial (slice blockIdx.z, no bias);
//           3 = bf16 silu(comp)*(acc+bias)  [SwiGLU fused w3 epilogue]
// Per K-tile: vmcnt(0) [loads issued a full tile earlier -> latency-hidden]
// -> s_barrier [tile resident + prev reads consumed] -> issue 8 staging
// loads of t+1 -> 24 ds_reads + 64 MFMA, compiler-interleaved (fine lgkmcnt).
template <int OUT_MODE>
__global__ __launch_bounds__(512, 2) void gemm256(
    const bf16_t* __restrict__ A, const bf16_t* __restrict__ B,
    const float* __restrict__ bias, const bf16_t* __restrict__ comp,
    void* __restrict__ Cout, int M, int N, int Kfull, int Klen) {
  __shared__ __align__(16) bf16_t Al[2][256][64];
  __shared__ __align__(16) bf16_t Bl[2][256][64];
  const int nTn = N >> 8;
  const int nwg = gridDim.x;
  const int bid = blockIdx.x;
  const int swz = ((nwg & 7) == 0) ? ((bid & 7) * (nwg >> 3) + (bid >> 3)) : bid;
  const int bm = swz / nTn, bn = swz % nTn;
  const int k0base = blockIdx.z * Klen;
  const int NT = Klen >> 6;
  const int tid = threadIdx.x, wid = tid >> 6, lane = tid & 63;
  const int wm2 = wid >> 2, wn = wid & 3;        // 2 x 4 waves
  const int lr = lane & 15, lg = lane >> 4;
  const int strow = wid * 8 + (lane >> 3);
  const int stg   = ((lane & 7) ^ ((lane >> 3) & 7)) << 3;
  const bf16_t* Abase = A + (size_t)(bm * 256 + strow) * Kfull + k0base + stg;
  const bf16_t* Bbase = B + (size_t)(bn * 256 + strow) * Kfull + k0base + stg;

#define STAGE_A(buf, half, c, t)                                              \
  GLOAD16(Abase + (size_t)((half) * 128 + (c) * 64) * Kfull + (t) * 64,       \
          &Al[buf][(half) * 128 + (c) * 64 + wid * 8][0])
#define STAGE_B(buf, half, c, t)                                              \
  GLOAD16(Bbase + (size_t)((half) * 128 + (c) * 64) * Kfull + (t) * 64,       \
          &Bl[buf][(half) * 128 + (c) * 64 + wid * 8][0])

  f32x4 acc[8][4] = {};
  // prologue: stage tile 0 into buf 0
  STAGE_A(0, 0, 0, 0); STAGE_A(0, 0, 1, 0); STAGE_A(0, 1, 0, 0); STAGE_A(0, 1, 1, 0);
  STAGE_B(0, 0, 0, 0); STAGE_B(0, 0, 1, 0); STAGE_B(0, 1, 0, 0); STAGE_B(0, 1, 1, 0);

  for (int t = 0; t < NT; ++t) {
    const int cur = t & 1, nxt = cur ^ 1;
    asm volatile("s_waitcnt vmcnt(0)" ::: "memory");   // tile t landed (mine)
    SBAR();                                            // all waves: tile t visible;
                                                       // t-1 reads all consumed
    if (t + 1 < NT) {                                  // stage t+1; rides thru tile
      STAGE_A(nxt, 0, 0, t + 1); STAGE_A(nxt, 0, 1, t + 1);
      STAGE_A(nxt, 1, 0, t + 1); STAGE_A(nxt, 1, 1, t + 1);
      STAGE_B(nxt, 0, 0, t + 1); STAGE_B(nxt, 0, 1, t + 1);
      STAGE_B(nxt, 1, 0, t + 1); STAGE_B(nxt, 1, 1, t + 1);
    }
    // k-chunk 0/1: read frags + 32 MFMA each; no fences -> compiler
    // interleaves ds_read/MFMA with fine-grained lgkmcnt.
#pragma unroll
    for (int ks = 0; ks < 2; ++ks) {
      bf16x8 af[8], bfr[4];
#pragma unroll
      for (int nf = 0; nf < 4; ++nf) {
        const int row = wn * 64 + nf * 16 + lr;
        const int g = ((ks * 4 + lg) ^ (lane & 7)) << 3;
        bfr[nf] = *reinterpret_cast<const bf16x8*>(&Bl[cur][row][g]);
      }
#pragma unroll
      for (int mf = 0; mf < 8; ++mf) {
        const int row = wm2 * 128 + mf * 16 + lr;
        const int g = ((ks * 4 + lg) ^ (lane & 7)) << 3;
        af[mf] = *reinterpret_cast<const bf16x8*>(&Al[cur][row][g]);
      }
      __builtin_amdgcn_s_setprio(1);
#pragma unroll
      for (int mf = 0; mf < 8; ++mf)
#pragma unroll
        for (int nf = 0; nf < 4; ++nf)
          acc[mf][nf] = __builtin_amdgcn_mfma_f32_16x16x32_bf16(af[mf], bfr[nf], acc[mf][nf], 0, 0, 0);
      __builtin_amdgcn_s_setprio(0);
    }
  }
#undef STAGE_A
#undef STAGE_B
  const int r0 = lg * 4;
#pragma unroll
  for (int mf = 0; mf < 8; ++mf) {
#pragma unroll
    for (int r = 0; r < 4; ++r) {
      const int row = bm * 256 + wm2 * 128 + mf * 16 + r0 + r;
#pragma unroll
      for (int nf = 0; nf < 4; ++nf) {
        const int col = bn * 256 + wn * 64 + nf * 16 + lr;
        float v = acc[mf][nf][r];
        if (OUT_MODE == 1) {
          v += bias[col];
          reinterpret_cast<bf16_t*>(Cout)[(size_t)row * N + col] = (bf16_t)v;
        } else if (OUT_MODE == 2) {
          float* P = reinterpret_cast<float*>(Cout) + (size_t)blockIdx.z * M * N;
          P[(size_t)row * N + col] = v;
        } else {
          v += bias[col];
          float c1 = (float)comp[(size_t)row * N + col];
          float sg = c1 / (1.0f + __expf(-c1));
          reinterpret_cast<bf16_t*>(Cout)[(size_t)row * N + col] = (bf16_t)(sg * v);
        }
      }
    }
  }
}

// ---------------- combine split-K partials + bias + residual ---------------
__global__ void combine_kernel(const float* __restrict__ part,
                               const float* __restrict__ bias,
                               const float* __restrict__ res,
                               float* __restrict__ out, int n4) {
  const int slice = NTOK * DIM / 4;
  int i = blockIdx.x * blockDim.x + threadIdx.x;
  int stride = gridDim.x * blockDim.x;
  const float4* p = reinterpret_cast<const float4*>(part);
  const float4* r4 = reinterpret_cast<const float4*>(res);
  const float4* b4 = reinterpret_cast<const float4*>(bias);
  float4* o4 = reinterpret_cast<float4*>(out);
  for (; i < n4; i += stride) {
    float4 a = p[i], b = p[i + slice], c = p[i + 2 * slice], d = p[i + 3 * slice];
    float4 rr = r4[i];
    float4 bb = b4[i & 255];
    float4 o;
    o.x = a.x + b.x + c.x + d.x + bb.x + rr.x;
    o.y = a.y + b.y + c.y + d.y + bb.y + rr.y;
    o.z = a.z + b.z + c.z + d.z + bb.z + rr.z;
    o.w = a.w + b.w + c.w + d.w + bb.w + rr.w;
    o4[i] = o;
  }
}

// ---------------- GEMM 128x128 (m97-style), out-proj ----------------------
// OUT_MODE: 0 = fp32 + bias + res; 2 = fp32 partial (slice z)
template <int OUT_MODE>
__global__ __launch_bounds__(256) void gemm_bt(
    const bf16_t* __restrict__ A, const bf16_t* __restrict__ B,
    const float* __restrict__ bias, const float* __restrict__ res,
    void* __restrict__ Cout, int M, int N, int Kfull, int Klen) {
  __shared__ bf16_t As[128][32];
  __shared__ bf16_t Bs[128][32];
  const int nTn = N >> 7;
  const int nwg = gridDim.x;
  const int bid = blockIdx.x;
  const int swz = ((nwg & 7) == 0) ? ((bid & 7) * (nwg >> 3) + (bid >> 3)) : bid;
  const int bm = swz / nTn;
  const int bn = swz % nTn;
  const int k0base = blockIdx.z * Klen;
  const int tid  = threadIdx.x;
  const int wid  = tid >> 6;
  const int lane = tid & 63;
  const int wm = (wid >> 1) * 64, wn = (wid & 1) * 64;
  const int lr = lane & 15;
  const int gq = lane >> 4;
  const int sr = lane >> 2;
  const int sg = lane & 3;
  const int cS = ((sg ^ ((sr >> 1) & 3)) << 3);
  const int swg = ((gq ^ ((lr >> 1) & 3)) << 3);
  f32x4 acc[4][4] = {};
  const bf16_t* Ag0 = A + (size_t)(bm * 128 + wid * 16 + sr) * Kfull + k0base + cS;
  const bf16_t* Ag1 = Ag0 + (size_t)64 * Kfull;
  const bf16_t* Bg0 = B + (size_t)(bn * 128 + wid * 16 + sr) * Kfull + k0base + cS;
  const bf16_t* Bg1 = Bg0 + (size_t)64 * Kfull;
  bf16_t* ldsA0 = &As[wid * 16][0];
  bf16_t* ldsA1 = &As[64 + wid * 16][0];
  bf16_t* ldsB0 = &Bs[wid * 16][0];
  bf16_t* ldsB1 = &Bs[64 + wid * 16][0];
  for (int k0 = 0; k0 < Klen; k0 += 32) {
    __syncthreads();
    GLOAD16(Ag0 + k0, ldsA0);
    GLOAD16(Ag1 + k0, ldsA1);
    GLOAD16(Bg0 + k0, ldsB0);
    GLOAD16(Bg1 + k0, ldsB1);
    __syncthreads();
    bf16x8 af[4], bfr[4];
#pragma unroll
    for (int mi = 0; mi < 4; ++mi)
      af[mi] = *reinterpret_cast<const bf16x8*>(&As[wm + mi * 16 + lr][swg]);
#pragma unroll
    for (int ni = 0; ni < 4; ++ni)
      bfr[ni] = *reinterpret_cast<const bf16x8*>(&Bs[wn + ni * 16 + lr][swg]);
#pragma unroll
    for (int mi = 0; mi < 4; ++mi)
#pragma unroll
      for (int ni = 0; ni < 4; ++ni)
        acc[mi][ni] = __builtin_amdgcn_mfma_f32_16x16x32_bf16(af[mi], bfr[ni], acc[mi][ni], 0, 0, 0);
  }
  const int r0 = (lane >> 4) * 4;
#pragma unroll
  for (int mi = 0; mi < 4; ++mi) {
#pragma unroll
    for (int r = 0; r < 4; ++r) {
      int row = bm * 128 + wm + mi * 16 + r0 + r;
#pragma unroll
      for (int ni = 0; ni < 4; ++ni) {
        int col = bn * 128 + wn + ni * 16 + lr;
        float v = acc[mi][ni][r];
        if (OUT_MODE == 0) {
          v += bias[col] + res[(size_t)row * N + col];
          reinterpret_cast<float*>(Cout)[(size_t)row * N + col] = v;
        } else {
          float* P = reinterpret_cast<float*>(Cout) + (size_t)blockIdx.z * M * N;
          P[(size_t)row * N + col] = v;
        }
      }
    }
  }
}

// ---------------- QK-norm (full-dim LN) + RoPE + BHSD repack ---------------
// Q pre-scaled by log2(e)/8 so attention computes p = 2^(s_raw) directly.
// RoPE pair (d^32) = lane^8's normalized value, fetched via shfl_xor (the
// pair's LN output is identical math to a scalar reload + renormalize).
__global__ __launch_bounds__(256) void qknorm_rope_kernel(
    const bf16_t* __restrict__ qkv,
    const float* __restrict__ qg, const float* __restrict__ qb,
    const float* __restrict__ kg, const float* __restrict__ kb,
    const float* __restrict__ rc, const float* __restrict__ rs,
    bf16_t* __restrict__ q_r, bf16_t* __restrict__ k_r) {
  int t = blockIdx.x;
  int b = t >> 11, s = t & 2047;
  const bf16_t* p = qkv + (size_t)t * 3072;
  int i = threadIdx.x;
  bf16x4 qv = *reinterpret_cast<const bf16x4*>(p + i * 4);
  bf16x4 kv = *reinterpret_cast<const bf16x4*>(p + 1024 + i * 4);
  float q4[4], k4[4];
  float sq = 0.f, sq2 = 0.f, sk = 0.f, sk2 = 0.f;
#pragma unroll
  for (int j = 0; j < 4; ++j) {
    q4[j] = (float)qv[j]; k4[j] = (float)kv[j];
    sq += q4[j]; sq2 += q4[j] * q4[j];
    sk += k4[j]; sk2 += k4[j] * k4[j];
  }
#pragma unroll
  for (int off = 32; off > 0; off >>= 1) {
    sq  += __shfl_down(sq, off, 64);
    sq2 += __shfl_down(sq2, off, 64);
    sk  += __shfl_down(sk, off, 64);
    sk2 += __shfl_down(sk2, off, 64);
  }
  __shared__ float red[4][4];
  int wid = i >> 6, lane = i & 63;
  if (lane == 0) { red[0][wid] = sq; red[1][wid] = sq2; red[2][wid] = sk; red[3][wid] = sk2; }
  __syncthreads();
  float Sq  = red[0][0] + red[0][1] + red[0][2] + red[0][3];
  float Sq2 = red[1][0] + red[1][1] + red[1][2] + red[1][3];
  float Sk  = red[2][0] + red[2][1] + red[2][2] + red[2][3];
  float Sk2 = red[3][0] + red[3][1] + red[3][2] + red[3][3];
  float mq = Sq * (1.0f / DIM);
  float vq = Sq2 * (1.0f / DIM) - mq * mq;
  float rq = rsqrtf(vq + 1e-6f);
  float mk = Sk * (1.0f / DIM);
  float vk = Sk2 * (1.0f / DIM) - mk * mk;
  float rk = rsqrtf(vk + 1e-6f);
  const float QS = 0.18033688011f;   // log2(e)/8 folded into Q
  // normalized values for own 4 elems
  float qn[4], kn[4];
#pragma unroll
  for (int j = 0; j < 4; ++j) {
    int d = i * 4 + j;
    qn[j] = (q4[j] - mq) * rq * qg[d] + qb[d];
    kn[j] = (k4[j] - mk) * rk * kg[d] + kb[d];
  }
#pragma unroll
  for (int j = 0; j < 4; ++j) {
    int d = i * 4 + j, h = d >> 6, hd = d & 63;
    float c  = rc[s * HD + hd];
    float sn = rs[s * HD + hd];
    float qpn = __shfl_xor(qn[j], 8, 64);   // normalized value at d^32
    float kpn = __shfl_xor(kn[j], 8, 64);
    float qo = qn[j] * c + ((hd < 32) ? -qpn : qpn) * sn;
    float ko = kn[j] * c + ((hd < 32) ? -kpn : kpn) * sn;
    size_t oi = ((size_t)(b * HEADS + h) * SEQ + s) * HD + hd;
    q_r[oi] = (bf16_t)(qo * QS);
    k_r[oi] = (bf16_t)ko;
  }
}

// ---------------- V transpose: qkv[b,s,2048+h*64+d] -> v_t[bh][d][s] -------
__global__ __launch_bounds__(256) void vtrans_kernel(
    const bf16_t* __restrict__ qkv, bf16_t* __restrict__ v_t) {
  __shared__ bf16_t T[64][72];
  const int st = blockIdx.x;
  const int bh = blockIdx.y;
  const int b = bh >> 4, h = bh & 15;
  const int tid = threadIdx.x;
  const int r = tid >> 2, c = (tid & 3) * 8;
  const bf16_t* src = qkv + (size_t)(b * SEQ + st * 64 + r) * 3072 + 2048 + h * 64;
  *reinterpret_cast<bf16x8*>(&T[r][c])      = *reinterpret_cast<const bf16x8*>(src + c);
  *reinterpret_cast<bf16x8*>(&T[r][c + 32]) = *reinterpret_cast<const bf16x8*>(src + c + 32);
  __syncthreads();
  bf16x8 o0, o1;
#pragma unroll
  for (int j = 0; j < 8; ++j) { o0[j] = T[c + j][r]; o1[j] = T[c + 32 + j][r]; }
  bf16_t* dst = v_t + ((size_t)bh * 64 + r) * SEQ + st * 64;
  *reinterpret_cast<bf16x8*>(dst + c)      = o0;
  *reinterpret_cast<bf16x8*>(dst + c + 32) = o1;
}

// ---------------- Flash attention: granule-major LDS + in-block K-split ----
__global__ __launch_bounds__(512, 2) void attn_kernel(
    const bf16_t* __restrict__ q_r, const bf16_t* __restrict__ k_r,
    const bf16_t* __restrict__ v_t, bf16_t* __restrict__ attn_out) {
  __shared__ __align__(16) char smem[69632];
  bf16_t* KsB = (bf16_t*)smem;
  bf16_t* VsB = (bf16_t*)(smem + 32768);
  float*  Xch = (float*)smem;
  const int bid = blockIdx.x;
  const int hh = bid & 31;
  const int qt = bid >> 5;
  const int bidx = hh >> 4, h = hh & 15;
  const int tid = threadIdx.x, wid = tid >> 6, lane = tid & 63;
  const int kh = wid >> 2, ww = wid & 3;
  const int lq = lane & 31, hi = lane >> 5;
  const int qA = qt * 256 + ww * 64 + lq;
  const int qB = qA + 32;
  const bf16_t* Qp = q_r + (size_t)hh * SEQ * HD;
  const bf16_t* Kp = k_r + (size_t)hh * SEQ * HD + (size_t)kh * 1024 * HD;
  const bf16_t* Vp = v_t + (size_t)hh * HD * SEQ + kh * 1024;
  bf16_t* Ks0 = KsB + kh * 2 * 4096;
  bf16_t* Vs0 = VsB + kh * 2 * 4096;
  bf16x8 qfA[4], qfB[4];
#pragma unroll
  for (int kdt = 0; kdt < 4; ++kdt) {
    qfA[kdt] = *reinterpret_cast<const bf16x8*>(Qp + (size_t)qA * HD + kdt * 16 + hi * 8);
    qfB[kdt] = *reinterpret_cast<const bf16x8*>(Qp + (size_t)qB * HD + kdt * 16 + hi * 8);
  }
  f32x16 oA0 = {}, oA1 = {}, oB0 = {}, oB1 = {};
  float lA = 0.f, lB = 0.f;
  const int kSrcA = lane * HD + ww * 8;
  const int kSrcB = lane * HD + (ww + 4) * 8;
  const int vSrcA = lane * SEQ + ww * 8;
  const int vSrcB = lane * SEQ + (ww + 4) * 8;
  const int ldsA = ww * 512;
  const int ldsB = 2048 + ww * 512;
  GLOAD16(Kp + kSrcA, &Ks0[ldsA]);
  GLOAD16(Kp + kSrcB, &Ks0[ldsB]);
  GLOAD16(Vp + vSrcA, &Vs0[ldsA]);
  GLOAD16(Vp + vSrcB, &Vs0[ldsB]);
  __syncthreads();
  const int NT = 1024 / 64;
  for (int kt = 0; kt < NT; ++kt) {
    const int cur = kt & 1, nxt = cur ^ 1;
    if (kt + 1 < NT) {
      GLOAD16(Kp + (kt + 1) * (64 * HD) + kSrcA, &Ks0[nxt * 4096 + ldsA]);
      GLOAD16(Kp + (kt + 1) * (64 * HD) + kSrcB, &Ks0[nxt * 4096 + ldsB]);
      GLOAD16(Vp + (kt + 1) * 64 + vSrcA, &Vs0[nxt * 4096 + ldsA]);
      GLOAD16(Vp + (kt + 1) * 64 + vSrcB, &Vs0[nxt * 4096 + ldsB]);
    }
    f32x16 sA0 = {}, sA1 = {}, sB0 = {}, sB1 = {};
#pragma unroll
    for (int kdt = 0; kdt < 4; ++kdt) {
      const int goff = cur * 4096 + (kdt * 2 + hi) * 512;
      bf16x8 kf0 = *reinterpret_cast<const bf16x8*>(&Ks0[goff + lq * 8]);
      bf16x8 kf1 = *reinterpret_cast<const bf16x8*>(&Ks0[goff + (lq + 32) * 8]);
      sA0 = __builtin_amdgcn_mfma_f32_32x32x16_bf16(kf0, qfA[kdt], sA0, 0, 0, 0);
      sA1 = __builtin_amdgcn_mfma_f32_32x32x16_bf16(kf1, qfA[kdt], sA1, 0, 0, 0);
      sB0 = __builtin_amdgcn_mfma_f32_32x32x16_bf16(kf0, qfB[kdt], sB0, 0, 0, 0);
      sB1 = __builtin_amdgcn_mfma_f32_32x32x16_bf16(kf1, qfB[kdt], sB1, 0, 0, 0);
    }
#pragma unroll
    for (int i = 0; i < 16; ++i) sA0[i] = __builtin_amdgcn_exp2f(sA0[i]);
#pragma unroll
    for (int i = 0; i < 16; ++i) sA1[i] = __builtin_amdgcn_exp2f(sA1[i]);
#pragma unroll
    for (int i = 0; i < 16; ++i) sB0[i] = __builtin_amdgcn_exp2f(sB0[i]);
#pragma unroll
    for (int i = 0; i < 16; ++i) sB1[i] = __builtin_amdgcn_exp2f(sB1[i]);
    {
      f32x16 t = sA0 + sA1;
      float a = ((t[0] + t[8]) + (t[4] + t[12])) + ((t[2] + t[10]) + (t[6] + t[14]));
      float b = ((t[1] + t[9]) + (t[5] + t[13])) + ((t[3] + t[11]) + (t[7] + t[15]));
      lA += a + b;
      f32x16 u = sB0 + sB1;
      float c = ((u[0] + u[8]) + (u[4] + u[12])) + ((u[2] + u[10]) + (u[6] + u[14]));
      float d = ((u[1] + u[9]) + (u[5] + u[13])) + ((u[3] + u[11]) + (u[7] + u[15]));
      lB += c + d;
    }
#pragma unroll
    for (int tt = 0; tt < 2; ++tt) {
#pragma unroll
      for (int ks = 0; ks < 2; ++ks) {
        const f32x16& pA = tt ? sA1 : sA0;
        const f32x16& pB = tt ? sB1 : sB0;
        unsigned a0, b0, c0, d0, a1, b1, c1, d1;
        if (ks == 0) {
          a0 = CVTPK(pA[0], pA[1]); b0 = CVTPK(pA[4], pA[5]);
          c0 = CVTPK(pA[2], pA[3]); d0 = CVTPK(pA[6], pA[7]);
          a1 = CVTPK(pB[0], pB[1]); b1 = CVTPK(pB[4], pB[5]);
          c1 = CVTPK(pB[2], pB[3]); d1 = CVTPK(pB[6], pB[7]);
        } else {
          a0 = CVTPK(pA[8], pA[9]);   b0 = CVTPK(pA[12], pA[13]);
          c0 = CVTPK(pA[10], pA[11]); d0 = CVTPK(pA[14], pA[15]);
          a1 = CVTPK(pB[8], pB[9]);   b1 = CVTPK(pB[12], pB[13]);
          c1 = CVTPK(pB[10], pB[11]); d1 = CVTPK(pB[14], pB[15]);
        }
        PLSWAP(a0, b0); PLSWAP(c0, d0); PLSWAP(a1, b1); PLSWAP(c1, d1);
        union { unsigned u[4]; bf16x8 v; } pfA, pfB;
        pfA.u[0] = a0; pfA.u[1] = c0; pfA.u[2] = b0; pfA.u[3] = d0;
        pfB.u[0] = a1; pfB.u[1] = c1; pfB.u[2] = b1; pfB.u[3] = d1;
        const int gv = cur * 4096 + (tt * 4 + ks * 2 + hi) * 512;
        bf16x8 vf0 = *reinterpret_cast<const bf16x8*>(&Vs0[gv + lq * 8]);
        bf16x8 vf1 = *reinterpret_cast<const bf16x8*>(&Vs0[gv + (lq + 32) * 8]);
        oA0 = __builtin_amdgcn_mfma_f32_32x32x16_bf16(vf0, pfA.v, oA0, 0, 0, 0);
        oA1 = __builtin_amdgcn_mfma_f32_32x32x16_bf16(vf1, pfA.v, oA1, 0, 0, 0);
        oB0 = __builtin_amdgcn_mfma_f32_32x32x16_bf16(vf0, pfB.v, oB0, 0, 0, 0);
        oB1 = __builtin_amdgcn_mfma_f32_32x32x16_bf16(vf1, pfB.v, oB1, 0, 0, 0);
      }
    }
    __syncthreads();
  }
  lA += __shfl_xor(lA, 32, 64);
  lB += __shfl_xor(lB, 32, 64);
  if (kh == 1) {
    float* my = Xch + (size_t)(ww * 64 + lane) * 68;
#pragma unroll
    for (int g = 0; g < 4; ++g) {
      *reinterpret_cast<float4*>(my + g * 4)      = make_float4(oA0[g*4], oA0[g*4+1], oA0[g*4+2], oA0[g*4+3]);
      *reinterpret_cast<float4*>(my + 16 + g * 4) = make_float4(oA1[g*4], oA1[g*4+1], oA1[g*4+2], oA1[g*4+3]);
      *reinterpret_cast<float4*>(my + 32 + g * 4) = make_float4(oB0[g*4], oB0[g*4+1], oB0[g*4+2], oB0[g*4+3]);
      *reinterpret_cast<float4*>(my + 48 + g * 4) = make_float4(oB1[g*4], oB1[g*4+1], oB1[g*4+2], oB1[g*4+3]);
    }
    my[64] = lA; my[65] = lB;
  }
  __syncthreads();
  if (kh == 0) {
    const float* pr = Xch + (size_t)(ww * 64 + lane) * 68;
#pragma unroll
    for (int i = 0; i < 16; ++i) {
      oA0[i] += pr[i];      oA1[i] += pr[16 + i];
      oB0[i] += pr[32 + i]; oB1[i] += pr[48 + i];
    }
    float invA = 1.0f / (lA + pr[64]);
    float invB = 1.0f / (lB + pr[65]);
    bf16_t* orowA = attn_out + ((size_t)(bidx * SEQ + qA)) * DIM + h * 64;
    bf16_t* orowB = attn_out + ((size_t)(bidx * SEQ + qB)) * DIM + h * 64;
#pragma unroll
    for (int g = 0; g < 4; ++g) {
      bf16x4 wA0, wA1, wB0, wB1;
#pragma unroll
      for (int j = 0; j < 4; ++j) {
        wA0[j] = (bf16_t)(oA0[g * 4 + j] * invA);
        wA1[j] = (bf16_t)(oA1[g * 4 + j] * invA);
        wB0[j] = (bf16_t)(oB0[g * 4 + j] * invB);
        wB1[j] = (bf16_t)(oB1[g * 4 + j] * invB);
      }
      *reinterpret_cast<bf16x4*>(orowA + g * 8 + 4 * hi)      = wA0;
      *reinterpret_cast<bf16x4*>(orowA + 32 + g * 8 + 4 * hi) = wA1;
      *reinterpret_cast<bf16x4*>(orowB + g * 8 + 4 * hi)      = wB0;
      *reinterpret_cast<bf16x4*>(orowB + 32 + g * 8 + 4 * hi) = wB1;
    }
  }
}

// ---------------------------------------------------------------------------
extern "C" void kernel_launch(void* const* d_in, const int* in_sizes, int n_in,
                              void* d_out, int out_size, void* d_ws, size_t ws_size,
                              hipStream_t stream) {
  const float* x        = (const float*)d_in[0];
  const float* rope_cos = (const float*)d_in[1];
  const float* rope_sin = (const float*)d_in[2];
  const float* w_qkv    = (const float*)d_in[3];
  const float* b_qkv    = (const float*)d_in[4];
  const float* w_out    = (const float*)d_in[5];
  const float* b_out    = (const float*)d_in[6];
  const float* qn_g     = (const float*)d_in[7];
  const float* qn_b     = (const float*)d_in[8];
  const float* kn_g     = (const float*)d_in[9];
  const float* kn_b     = (const float*)d_in[10];
  const float* ln1_g    = (const float*)d_in[11];
  const float* ln1_b    = (const float*)d_in[12];
  const float* ln2_g    = (const float*)d_in[13];
  const float* ln2_b    = (const float*)d_in[14];
  const float* w1       = (const float*)d_in[15];
  const float* b1       = (const float*)d_in[16];
  const float* w2       = (const float*)d_in[17];
  const float* b2       = (const float*)d_in[18];
  const float* w3       = (const float*)d_in[19];
  const float* b3       = (const float*)d_in[20];

  const size_t OFF_WQKV = 0;
  const size_t OFF_WOUT = 6291456;
  const size_t OFF_W1   = 8388608;
  const size_t OFF_W2   = 16777216;
  const size_t OFF_W3   = 25165824;
  const size_t OFF_H1   = 33554432;
  const size_t OFF_QKV  = 41943040;
  const size_t OFF_QR   = 67108864;
  const size_t OFF_KR   = 75497472;
  const size_t OFF_VT   = 83886080;
  const size_t OFF_ATT  = 92274688;
  const size_t OFF_X2   = 100663296;
  const size_t OFF_H2   = 117440512;
  const size_t OFF_PART = 125829120;  // 4 x 16MB fp32 split-K partials (w2)
  const size_t NEEDED   = 125829120;
  const size_t NEED_SPLIT = OFF_PART + 67108864;
  if (ws_size < NEEDED) return;
  const bool use_split = (ws_size >= NEED_SPLIT);

  char* ws = (char*)d_ws;
  bf16_t* wqkv_bf = (bf16_t*)(ws + OFF_WQKV);
  bf16_t* wout_bf = (bf16_t*)(ws + OFF_WOUT);
  bf16_t* w1_bf   = (bf16_t*)(ws + OFF_W1);
  bf16_t* w2_bf   = (bf16_t*)(ws + OFF_W2);
  bf16_t* w3_bf   = (bf16_t*)(ws + OFF_W3);
  bf16_t* h1      = (bf16_t*)(ws + OFF_H1);
  bf16_t* qkv     = (bf16_t*)(ws + OFF_QKV);
  bf16_t* q_r     = (bf16_t*)(ws + OFF_QR);
  bf16_t* k_r     = (bf16_t*)(ws + OFF_KR);
  bf16_t* v_t     = (bf16_t*)(ws + OFF_VT);
  bf16_t* att     = (bf16_t*)(ws + OFF_ATT);
  float*  x2      = (float*)(ws + OFF_X2);
  bf16_t* h2      = (bf16_t*)(ws + OFF_H2);
  bf16_t* a1      = (bf16_t*)(ws + OFF_H1);   // reuse h1+qkv (dead by FFN)
  bf16_t* a3      = (bf16_t*)(ws + OFF_QR);   // reuse q/k/vt/att (dead by FFN)
  float*  part    = (float*)(ws + OFF_PART);
  float*  out     = (float*)d_out;

  f2bf_all_kernel<<<2048, 256, 0, stream>>>(w_qkv, w_out, w1, w2, w3,
                                            wqkv_bf, wout_bf, w1_bf, w2_bf, w3_bf);
  ln_kernel<<<NTOK, 256, 0, stream>>>(x, ln1_g, ln1_b, h1);
  gemm256<1><<<dim3(192, 1, 1), 512, 0, stream>>>(h1, wqkv_bf, b_qkv, nullptr, qkv,
                                                  NTOK, 3072, DIM, DIM);
  qknorm_rope_kernel<<<NTOK, 256, 0, stream>>>(qkv, qn_g, qn_b, kn_g, kn_b,
                                               rope_cos, rope_sin, q_r, k_r);
  vtrans_kernel<<<dim3(SEQ / 64, NB * HEADS), 256, 0, stream>>>(qkv, v_t);
  attn_kernel<<<256, 512, 0, stream>>>(q_r, k_r, v_t, att);
  gemm_bt<0><<<dim3(32 * 8, 1, 1), 256, 0, stream>>>(
      att, wout_bf, b_out, x, x2, NTOK, DIM, DIM, DIM);
  ln_kernel<<<NTOK, 256, 0, stream>>>(x2, ln2_g, ln2_b, h2);
  gemm256<1><<<dim3(256, 1, 1), 512, 0, stream>>>(h2, w1_bf, b1, nullptr, a1,
                                                  NTOK, FFND, DIM, DIM);
  gemm256<3><<<dim3(256, 1, 1), 512, 0, stream>>>(h2, w3_bf, b3, a1, a3,
                                                  NTOK, FFND, DIM, DIM);
  if (use_split) {
    gemm256<2><<<dim3(64, 1, 4), 512, 0, stream>>>(a3, w2_bf, nullptr, nullptr, part,
                                                   NTOK, DIM, FFND, FFND / 4);
    combine_kernel<<<2048, 256, 0, stream>>>(part, b2, x2, out, NTOK * DIM / 4);
  } else {
    gemm_bt<0><<<dim3(32 * 8, 1, 1), 256, 0, stream>>>(
        a3, w2_bf, b2, x2, out, NTOK, DIM, FFND, FFND);
  }
}